// Round 1
// baseline (615.099 us; speedup 1.0000x reference)
//
#include <hip/hip_runtime.h>
#include <math.h>

#define N_NODES   80000
#define NU_NODES  40000
#define E_EDGES   1280000
#define B_PAIRS   8192
#define NEG_SLOPE 0.2f

// ---------------- CSR build ----------------

__global__ void hist_kernel(const int* __restrict__ dst, int* __restrict__ counts, int E) {
    int e = blockIdx.x * 256 + threadIdx.x;
    if (e < E) atomicAdd(&counts[dst[e]], 1);
}

__global__ void scan_blocks_kernel(const int* __restrict__ counts, int* __restrict__ row_ptr,
                                   int* __restrict__ bsums, int n) {
    __shared__ int tmp[1024];
    int gid = blockIdx.x * 1024 + threadIdx.x;
    int v = (gid < n) ? counts[gid] : 0;
    tmp[threadIdx.x] = v;
    __syncthreads();
    for (int off = 1; off < 1024; off <<= 1) {
        int t = (threadIdx.x >= off) ? tmp[threadIdx.x - off] : 0;
        __syncthreads();
        tmp[threadIdx.x] += t;
        __syncthreads();
    }
    if (gid < n) row_ptr[gid + 1] = tmp[threadIdx.x];
    if (threadIdx.x == 1023) bsums[blockIdx.x] = tmp[1023];
}

__global__ void scan_sums_kernel(int* bsums, int nb) {
    __shared__ int tmp[256];
    int v = (threadIdx.x < nb) ? bsums[threadIdx.x] : 0;
    tmp[threadIdx.x] = v;
    __syncthreads();
    for (int off = 1; off < 256; off <<= 1) {
        int t = (threadIdx.x >= off) ? tmp[threadIdx.x - off] : 0;
        __syncthreads();
        tmp[threadIdx.x] += t;
        __syncthreads();
    }
    if (threadIdx.x < nb) bsums[threadIdx.x] = tmp[threadIdx.x] - v;  // exclusive
}

__global__ void add_offsets_kernel(int* row_ptr, const int* __restrict__ bsums, int n) {
    int gid = blockIdx.x * 256 + threadIdx.x;
    if (gid < n) row_ptr[gid + 1] += bsums[gid >> 10];
    if (gid == 0) row_ptr[0] = 0;
}

__global__ void scatter_kernel(const int* __restrict__ srcArr, const int* __restrict__ dstArr,
                               const int* __restrict__ row_ptr, int* __restrict__ fill,
                               int* __restrict__ src_sorted, int E) {
    int e = blockIdx.x * 256 + threadIdx.x;
    if (e < E) {
        int d = dstArr[e];
        int pos = atomicAdd(&fill[d], 1);
        src_sorted[row_ptr[d] + pos] = srcArr[e];
    }
}

// ---------------- GEMM: [M,K] @ [K,128] -> [M,128], M multiple of 32 ----------------

template <int K>
__global__ __launch_bounds__(256) void gemm_kernel(const float* __restrict__ A,
                                                   const float* __restrict__ W,
                                                   float* __restrict__ out) {
    __shared__ float Wl[K * 128];
    __shared__ float As[32][K];
    int row0 = blockIdx.x * 32;
    for (int i = threadIdx.x; i < K * 128; i += 256) Wl[i] = W[i];
    for (int i = threadIdx.x; i < 32 * K; i += 256) {
        int r = i / K, k = i - r * K;
        As[r][k] = A[(size_t)(row0 + r) * K + k];
    }
    __syncthreads();
    int c  = threadIdx.x & 63;
    int rg = threadIdx.x >> 6;  // 0..3, uniform per wave -> As reads broadcast
    float acc0[8] = {0,0,0,0,0,0,0,0};
    float acc1[8] = {0,0,0,0,0,0,0,0};
    for (int k = 0; k < K; ++k) {
        float b0 = Wl[k * 128 + c];
        float b1 = Wl[k * 128 + 64 + c];
#pragma unroll
        for (int r = 0; r < 8; ++r) {
            float a = As[rg * 8 + r][k];
            acc0[r] = fmaf(a, b0, acc0[r]);
            acc1[r] = fmaf(a, b1, acc1[r]);
        }
    }
#pragma unroll
    for (int r = 0; r < 8; ++r) {
        int row = row0 + rg * 8 + r;
        out[(size_t)row * 128 + c]      = acc0[r];
        out[(size_t)row * 128 + 64 + c] = acc1[r];
    }
}

// ---------------- per-(node,head) attention dots ----------------

__global__ void att_dots_kernel(const float* __restrict__ h, const float* __restrict__ att_s,
                                const float* __restrict__ att_d, float* __restrict__ a_s,
                                float* __restrict__ a_d, int NH) {
    int w    = blockIdx.x * 4 + (threadIdx.x >> 6);
    int lane = threadIdx.x & 63;
    if (w >= NH) return;
    int hh  = w & 1;  // H == 2
    float v = h[(size_t)w * 64 + lane];
    float s = v * att_s[hh * 64 + lane];
    float d = v * att_d[hh * 64 + lane];
    for (int o = 32; o; o >>= 1) {
        s += __shfl_xor(s, o);
        d += __shfl_xor(d, o);
    }
    if (lane == 0) { a_s[w] = s; a_d[w] = d; }
}

// ---------------- GAT aggregation: one block per dst node, wave per head ----------------

template <bool CONCAT>
__global__ void gat_agg_kernel(const float* __restrict__ h, const int* __restrict__ row_ptr,
                               const int* __restrict__ src_sorted, const float* __restrict__ a_s,
                               const float* __restrict__ a_d, const float* __restrict__ bias,
                               float* __restrict__ out) {
    int dnode = blockIdx.x;
    int hh    = threadIdx.x >> 6;  // head, uniform per wave
    int lane  = threadIdx.x & 63;  // channel
    int start = row_ptr[dnode], end = row_ptr[dnode + 1];
    float adst = a_d[dnode * 2 + hh];

    // pass 1: edge-parallel max
    float m = -INFINITY;
    for (int k = start + lane; k < end; k += 64) {
        int s   = src_sorted[k];
        float v = a_s[s * 2 + hh] + adst;
        v = v > 0.f ? v : NEG_SLOPE * v;
        m = fmaxf(m, v);
    }
    for (int o = 32; o; o >>= 1) m = fmaxf(m, __shfl_xor(m, o));

    // pass 2: serial over edges, channel-parallel accumulate
    float acc = 0.f, denom = 0.f;
    for (int k = start; k < end; ++k) {
        int s   = src_sorted[k];
        float v = a_s[s * 2 + hh] + adst;
        v = v > 0.f ? v : NEG_SLOPE * v;
        float wgt = __expf(v - m);
        denom += wgt;  // identical in all lanes
        acc += wgt * h[(size_t)s * 128 + hh * 64 + lane];
    }
    float r = acc / (denom + 1e-16f);

    if (CONCAT) {
        out[(size_t)dnode * 128 + hh * 64 + lane] = r + bias[hh * 64 + lane];
    } else {
        __shared__ float tmp[128];
        tmp[threadIdx.x] = r;
        __syncthreads();
        if (threadIdx.x < 64)
            out[(size_t)dnode * 64 + lane] = 0.5f * (tmp[lane] + tmp[64 + lane]) + bias[lane];
    }
}

// ---------------- final pair dot ----------------

__global__ void pair_dot_kernel(const float* __restrict__ emb, const int* __restrict__ ui,
                                const int* __restrict__ ii, float* __restrict__ out, int B) {
    int w    = blockIdx.x * 4 + (threadIdx.x >> 6);
    int lane = threadIdx.x & 63;
    if (w >= B) return;
    float a = emb[(size_t)ui[w] * 64 + lane];
    float b = emb[(size_t)(NU_NODES + ii[w]) * 64 + lane];
    float p = a * b;
    for (int o = 32; o; o >>= 1) p += __shfl_xor(p, o);
    if (lane == 0) out[w] = p;
}

extern "C" void kernel_launch(void* const* d_in, const int* in_sizes, int n_in,
                              void* d_out, int out_size, void* d_ws, size_t ws_size,
                              hipStream_t stream) {
    const float* Gu       = (const float*)d_in[0];
    const float* Gi       = (const float*)d_in[1];
    const float* W0       = (const float*)d_in[2];
    const float* att_src0 = (const float*)d_in[3];
    const float* att_dst0 = (const float*)d_in[4];
    const float* b0       = (const float*)d_in[5];
    const float* W1       = (const float*)d_in[6];
    const float* att_src1 = (const float*)d_in[7];
    const float* att_dst1 = (const float*)d_in[8];
    const float* b1       = (const float*)d_in[9];
    const int* edge_index = (const int*)d_in[10];
    const int* user_idx   = (const int*)d_in[11];
    const int* item_idx   = (const int*)d_in[12];
    float* outp           = (float*)d_out;

    const int N = N_NODES, E = E_EDGES;
    char* wsp = (char*)d_ws;
    auto alloc = [&](size_t bytes) {
        void* p = wsp;
        wsp += (bytes + 255) & ~(size_t)255;
        return p;
    };
    float* x0  = (float*)alloc((size_t)N * 64 * 4);   // layer0 input; reused as final emb
    float* h   = (float*)alloc((size_t)N * 128 * 4);  // h0, then h1
    float* x1  = (float*)alloc((size_t)N * 128 * 4);  // layer0 output
    float* a_s = (float*)alloc((size_t)N * 2 * 4);
    float* a_d = (float*)alloc((size_t)N * 2 * 4);
    int* row_ptr    = (int*)alloc((size_t)(N + 1) * 4);
    int* counts     = (int*)alloc((size_t)N * 4);
    int* fill       = (int*)alloc((size_t)N * 4);
    int* bsums      = (int*)alloc(256 * 4);
    int* src_sorted = (int*)alloc((size_t)E * 4);

    const int* esrc = edge_index;
    const int* edst = edge_index + E;

    // CSR by dst
    hipMemsetAsync(counts, 0, (size_t)N * 4, stream);
    hipMemsetAsync(fill, 0, (size_t)N * 4, stream);
    hist_kernel<<<E / 256, 256, 0, stream>>>(edst, counts, E);
    int nb = (N + 1023) / 1024;
    scan_blocks_kernel<<<nb, 1024, 0, stream>>>(counts, row_ptr, bsums, N);
    scan_sums_kernel<<<1, 256, 0, stream>>>(bsums, nb);
    add_offsets_kernel<<<(N + 255) / 256, 256, 0, stream>>>(row_ptr, bsums, N);
    scatter_kernel<<<E / 256, 256, 0, stream>>>(esrc, edst, row_ptr, fill, src_sorted, E);

    // x0 = concat(Gu, Gi)
    hipMemcpyAsync(x0, Gu, (size_t)NU_NODES * 64 * 4, hipMemcpyDeviceToDevice, stream);
    hipMemcpyAsync(x0 + (size_t)NU_NODES * 64, Gi, (size_t)NU_NODES * 64 * 4,
                   hipMemcpyDeviceToDevice, stream);

    // layer 0
    gemm_kernel<64><<<N / 32, 256, 0, stream>>>(x0, W0, h);
    att_dots_kernel<<<(N * 2) / 4, 256, 0, stream>>>(h, att_src0, att_dst0, a_s, a_d, N * 2);
    gat_agg_kernel<true><<<N, 128, 0, stream>>>(h, row_ptr, src_sorted, a_s, a_d, b0, x1);

    // layer 1
    gemm_kernel<128><<<N / 32, 256, 0, stream>>>(x1, W1, h);
    att_dots_kernel<<<(N * 2) / 4, 256, 0, stream>>>(h, att_src1, att_dst1, a_s, a_d, N * 2);
    gat_agg_kernel<false><<<N, 128, 0, stream>>>(h, row_ptr, src_sorted, a_s, a_d, b1, x0);

    // final dot
    pair_dot_kernel<<<B_PAIRS / 4, 256, 0, stream>>>(x0, user_idx, item_idx, outp, B_PAIRS);
}

// Round 2
// 476.820 us; speedup vs baseline: 1.2900x; 1.2900x over previous
//
#include <hip/hip_runtime.h>
#include <math.h>

#define N_NODES   80000
#define NU_NODES  40000
#define E_EDGES   1280000
#define B_PAIRS   8192
#define NEG_SLOPE 0.2f

// ---------------- CSR build ----------------

__global__ void hist_kernel(const int* __restrict__ dst, int* __restrict__ counts, int E) {
    int e = blockIdx.x * 256 + threadIdx.x;
    if (e < E) atomicAdd(&counts[dst[e]], 1);
}

__global__ void scan_blocks_kernel(const int* __restrict__ counts, int* __restrict__ row_ptr,
                                   int* __restrict__ bsums, int n) {
    __shared__ int tmp[1024];
    int gid = blockIdx.x * 1024 + threadIdx.x;
    int v = (gid < n) ? counts[gid] : 0;
    tmp[threadIdx.x] = v;
    __syncthreads();
    for (int off = 1; off < 1024; off <<= 1) {
        int t = (threadIdx.x >= off) ? tmp[threadIdx.x - off] : 0;
        __syncthreads();
        tmp[threadIdx.x] += t;
        __syncthreads();
    }
    if (gid < n) row_ptr[gid + 1] = tmp[threadIdx.x];
    if (threadIdx.x == 1023) bsums[blockIdx.x] = tmp[1023];
}

__global__ void scan_sums_kernel(int* bsums, int nb) {
    __shared__ int tmp[256];
    int v = (threadIdx.x < nb) ? bsums[threadIdx.x] : 0;
    tmp[threadIdx.x] = v;
    __syncthreads();
    for (int off = 1; off < 256; off <<= 1) {
        int t = (threadIdx.x >= off) ? tmp[threadIdx.x - off] : 0;
        __syncthreads();
        tmp[threadIdx.x] += t;
        __syncthreads();
    }
    if (threadIdx.x < nb) bsums[threadIdx.x] = tmp[threadIdx.x] - v;  // exclusive
}

__global__ void add_offsets_kernel(int* row_ptr, const int* __restrict__ bsums, int n) {
    int gid = blockIdx.x * 256 + threadIdx.x;
    if (gid < n) row_ptr[gid + 1] += bsums[gid >> 10];
    if (gid == 0) row_ptr[0] = 0;
}

__global__ void scatter_kernel(const int* __restrict__ srcArr, const int* __restrict__ dstArr,
                               const int* __restrict__ row_ptr, int* __restrict__ fill,
                               int* __restrict__ src_sorted, int E) {
    int e = blockIdx.x * 256 + threadIdx.x;
    if (e < E) {
        int d = dstArr[e];
        int pos = atomicAdd(&fill[d], 1);
        src_sorted[row_ptr[d] + pos] = srcArr[e];
    }
}

// ---------------- GEMM: [M,K] @ [K,128] -> [M,128] ----------------
// A split across two base pointers at row `split` (for the Gu/Gi concat).
// blockIdx covers 32 rows; 40000 % 32 == 0 so a block never straddles split.

template <int K>
__global__ __launch_bounds__(256) void gemm_kernel(const float* __restrict__ A0,
                                                   const float* __restrict__ A1, int split,
                                                   const float* __restrict__ W,
                                                   float* __restrict__ out) {
    __shared__ float Wl[K * 128];
    __shared__ float As[32][K];
    int row0 = blockIdx.x * 32;
    const float* A = (row0 < split) ? (A0 + (size_t)row0 * K) : (A1 + (size_t)(row0 - split) * K);
    for (int i = threadIdx.x; i < K * 128 / 4; i += 256)
        ((float4*)Wl)[i] = ((const float4*)W)[i];
    for (int i = threadIdx.x; i < 32 * K / 4; i += 256)
        ((float4*)&As[0][0])[i] = ((const float4*)A)[i];
    __syncthreads();
    int c  = threadIdx.x & 63;
    int rg = threadIdx.x >> 6;  // 0..3, uniform per wave -> As reads broadcast
    float acc0[8] = {0,0,0,0,0,0,0,0};
    float acc1[8] = {0,0,0,0,0,0,0,0};
    for (int k4 = 0; k4 < K; k4 += 4) {
        float4 a[8];
#pragma unroll
        for (int r = 0; r < 8; ++r) a[r] = *(const float4*)&As[rg * 8 + r][k4];
#pragma unroll
        for (int kk = 0; kk < 4; ++kk) {
            float b0 = Wl[(k4 + kk) * 128 + c];
            float b1 = Wl[(k4 + kk) * 128 + 64 + c];
#pragma unroll
            for (int r = 0; r < 8; ++r) {
                float av = kk == 0 ? a[r].x : kk == 1 ? a[r].y : kk == 2 ? a[r].z : a[r].w;
                acc0[r] = fmaf(av, b0, acc0[r]);
                acc1[r] = fmaf(av, b1, acc1[r]);
            }
        }
    }
#pragma unroll
    for (int r = 0; r < 8; ++r) {
        int row = row0 + rg * 8 + r;
        out[(size_t)row * 128 + c]      = acc0[r];
        out[(size_t)row * 128 + 64 + c] = acc1[r];
    }
}

// ---------------- attention dots: one wave per node, both heads ----------------

__global__ __launch_bounds__(256) void att_dots_kernel(const float* __restrict__ h,
                                const float* __restrict__ att_s,
                                const float* __restrict__ att_d, float* __restrict__ a_s,
                                float* __restrict__ a_d, int N) {
    int w    = blockIdx.x * 4 + (threadIdx.x >> 6);
    int lane = threadIdx.x & 63;
    if (w >= N) return;
    float2 v  = *(const float2*)(h + (size_t)w * 128 + lane * 2);
    float2 cs = *(const float2*)(att_s + lane * 2);
    float2 cd = *(const float2*)(att_d + lane * 2);
    float s = v.x * cs.x + v.y * cs.y;
    float d = v.x * cd.x + v.y * cd.y;
    for (int o = 16; o; o >>= 1) { s += __shfl_xor(s, o); d += __shfl_xor(d, o); }
    if ((lane & 31) == 0) {
        int hh = lane >> 5;
        a_s[w * 2 + hh] = s;
        a_d[w * 2 + hh] = d;
    }
}

// ---------------- GAT aggregation: one WAVE per dst node, both heads ----------------
// lane covers channels (2*lane, 2*lane+1) of the concat [H*C]=128; head = lane>>5.

template <bool CONCAT>
__global__ __launch_bounds__(256) void gat_agg_kernel(const float* __restrict__ h,
        const int* __restrict__ row_ptr, const int* __restrict__ src_sorted,
        const float* __restrict__ a_s, const float* __restrict__ a_d,
        const float* __restrict__ bias, float* __restrict__ out) {
    __shared__ int   s_idx[4][64];
    __shared__ float s_w[4][64][2];
    int wid   = threadIdx.x >> 6;
    int lane  = threadIdx.x & 63;
    int dnode = blockIdx.x * 4 + wid;
    if (dnode >= N_NODES) return;
    int start = row_ptr[dnode], end = row_ptr[dnode + 1];
    int deg = end - start;
    float2 ad = *(const float2*)(a_d + dnode * 2);
    int hh = lane >> 5;
    float2 acc = {0.f, 0.f};
    float den0 = 0.f, den1 = 0.f;

    if (deg <= 64) {  // fast path: edge data stays in registers across max-reduce
        float v0 = -INFINITY, v1 = -INFINITY;
        int s = 0;
        if (lane < deg) {
            s = src_sorted[start + lane];
            float2 as = *(const float2*)(a_s + s * 2);
            v0 = as.x + ad.x; v0 = v0 > 0.f ? v0 : NEG_SLOPE * v0;
            v1 = as.y + ad.y; v1 = v1 > 0.f ? v1 : NEG_SLOPE * v1;
        }
        float m0 = v0, m1 = v1;
        for (int o = 32; o; o >>= 1) {
            m0 = fmaxf(m0, __shfl_xor(m0, o));
            m1 = fmaxf(m1, __shfl_xor(m1, o));
        }
        if (lane < deg) {
            float w0 = __expf(v0 - m0), w1 = __expf(v1 - m1);
            den0 = w0; den1 = w1;
            s_idx[wid][lane] = s;
            s_w[wid][lane][0] = w0;
            s_w[wid][lane][1] = w1;
        }
        for (int j = 0; j < deg; ++j) {
            int  si = s_idx[wid][j];
            float w = s_w[wid][j][hh];
            float2 v = *(const float2*)(h + (size_t)si * 128 + lane * 2);
            acc.x = fmaf(w, v.x, acc.x);
            acc.y = fmaf(w, v.y, acc.y);
        }
    } else {  // general path (vanishingly rare for Poisson(16) degrees)
        float m0 = -INFINITY, m1 = -INFINITY;
        for (int k = start + lane; k < end; k += 64) {
            int s = src_sorted[k];
            float2 as = *(const float2*)(a_s + s * 2);
            float v0 = as.x + ad.x; v0 = v0 > 0.f ? v0 : NEG_SLOPE * v0;
            float v1 = as.y + ad.y; v1 = v1 > 0.f ? v1 : NEG_SLOPE * v1;
            m0 = fmaxf(m0, v0); m1 = fmaxf(m1, v1);
        }
        for (int o = 32; o; o >>= 1) {
            m0 = fmaxf(m0, __shfl_xor(m0, o));
            m1 = fmaxf(m1, __shfl_xor(m1, o));
        }
        for (int c0 = start; c0 < end; c0 += 64) {
            int len = min(64, end - c0);
            if (lane < len) {
                int s = src_sorted[c0 + lane];
                float2 as = *(const float2*)(a_s + s * 2);
                float v0 = as.x + ad.x; v0 = v0 > 0.f ? v0 : NEG_SLOPE * v0;
                float v1 = as.y + ad.y; v1 = v1 > 0.f ? v1 : NEG_SLOPE * v1;
                float w0 = __expf(v0 - m0), w1 = __expf(v1 - m1);
                den0 += w0; den1 += w1;
                s_idx[wid][lane] = s;
                s_w[wid][lane][0] = w0;
                s_w[wid][lane][1] = w1;
            }
            for (int j = 0; j < len; ++j) {
                int  si = s_idx[wid][j];
                float w = s_w[wid][j][hh];
                float2 v = *(const float2*)(h + (size_t)si * 128 + lane * 2);
                acc.x = fmaf(w, v.x, acc.x);
                acc.y = fmaf(w, v.y, acc.y);
            }
        }
    }

    for (int o = 32; o; o >>= 1) {
        den0 += __shfl_xor(den0, o);
        den1 += __shfl_xor(den1, o);
    }
    float inv = 1.f / ((hh ? den1 : den0) + 1e-16f);
    float2 r = {acc.x * inv, acc.y * inv};

    if (CONCAT) {
        float2 b = *(const float2*)(bias + lane * 2);
        float2 o2 = {r.x + b.x, r.y + b.y};
        *(float2*)(out + (size_t)dnode * 128 + lane * 2) = o2;
    } else {
        float ox = __shfl_xor(r.x, 32);
        float oy = __shfl_xor(r.y, 32);
        if (lane < 32) {
            float2 b = *(const float2*)(bias + lane * 2);
            float2 o2 = {0.5f * (r.x + ox) + b.x, 0.5f * (r.y + oy) + b.y};
            *(float2*)(out + (size_t)dnode * 64 + lane * 2) = o2;
        }
    }
}

// ---------------- final pair dot ----------------

__global__ void pair_dot_kernel(const float* __restrict__ emb, const int* __restrict__ ui,
                                const int* __restrict__ ii, float* __restrict__ out, int B) {
    int w    = blockIdx.x * 4 + (threadIdx.x >> 6);
    int lane = threadIdx.x & 63;
    if (w >= B) return;
    float a = emb[(size_t)ui[w] * 64 + lane];
    float b = emb[(size_t)(NU_NODES + ii[w]) * 64 + lane];
    float p = a * b;
    for (int o = 32; o; o >>= 1) p += __shfl_xor(p, o);
    if (lane == 0) out[w] = p;
}

extern "C" void kernel_launch(void* const* d_in, const int* in_sizes, int n_in,
                              void* d_out, int out_size, void* d_ws, size_t ws_size,
                              hipStream_t stream) {
    const float* Gu       = (const float*)d_in[0];
    const float* Gi       = (const float*)d_in[1];
    const float* W0       = (const float*)d_in[2];
    const float* att_src0 = (const float*)d_in[3];
    const float* att_dst0 = (const float*)d_in[4];
    const float* b0       = (const float*)d_in[5];
    const float* W1       = (const float*)d_in[6];
    const float* att_src1 = (const float*)d_in[7];
    const float* att_dst1 = (const float*)d_in[8];
    const float* b1       = (const float*)d_in[9];
    const int* edge_index = (const int*)d_in[10];
    const int* user_idx   = (const int*)d_in[11];
    const int* item_idx   = (const int*)d_in[12];
    float* outp           = (float*)d_out;

    const int N = N_NODES, E = E_EDGES;
    char* wsp = (char*)d_ws;
    auto alloc = [&](size_t bytes) {
        void* p = wsp;
        wsp += (bytes + 255) & ~(size_t)255;
        return p;
    };
    float* emb = (float*)alloc((size_t)N * 64 * 4);   // final embeddings
    float* h   = (float*)alloc((size_t)N * 128 * 4);  // h0, then h1
    float* x1  = (float*)alloc((size_t)N * 128 * 4);  // layer0 output
    float* a_s = (float*)alloc((size_t)N * 2 * 4);
    float* a_d = (float*)alloc((size_t)N * 2 * 4);
    int* row_ptr    = (int*)alloc((size_t)(N + 1) * 4);
    int* counts     = (int*)alloc((size_t)N * 4);
    int* fill       = (int*)alloc((size_t)N * 4);
    int* bsums      = (int*)alloc(256 * 4);
    int* src_sorted = (int*)alloc((size_t)E * 4);

    const int* esrc = edge_index;
    const int* edst = edge_index + E;

    // CSR by dst
    hipMemsetAsync(counts, 0, (size_t)N * 4, stream);
    hipMemsetAsync(fill, 0, (size_t)N * 4, stream);
    hist_kernel<<<E / 256, 256, 0, stream>>>(edst, counts, E);
    int nb = (N + 1023) / 1024;
    scan_blocks_kernel<<<nb, 1024, 0, stream>>>(counts, row_ptr, bsums, N);
    scan_sums_kernel<<<1, 256, 0, stream>>>(bsums, nb);
    add_offsets_kernel<<<(N + 255) / 256, 256, 0, stream>>>(row_ptr, bsums, N);
    scatter_kernel<<<E / 256, 256, 0, stream>>>(esrc, edst, row_ptr, fill, src_sorted, E);

    // layer 0  (A read directly from Gu/Gi, no concat copy)
    gemm_kernel<64><<<N / 32, 256, 0, stream>>>(Gu, Gi, NU_NODES, W0, h);
    att_dots_kernel<<<(N + 3) / 4, 256, 0, stream>>>(h, att_src0, att_dst0, a_s, a_d, N);
    gat_agg_kernel<true><<<(N + 3) / 4, 256, 0, stream>>>(h, row_ptr, src_sorted, a_s, a_d, b0, x1);

    // layer 1
    gemm_kernel<128><<<N / 32, 256, 0, stream>>>(x1, x1, N, W1, h);
    att_dots_kernel<<<(N + 3) / 4, 256, 0, stream>>>(h, att_src1, att_dst1, a_s, a_d, N);
    gat_agg_kernel<false><<<(N + 3) / 4, 256, 0, stream>>>(h, row_ptr, src_sorted, a_s, a_d, b1, emb);

    // final dot
    pair_dot_kernel<<<B_PAIRS / 4, 256, 0, stream>>>(emb, user_idx, item_idx, outp, B_PAIRS);
}

// Round 3
// 443.253 us; speedup vs baseline: 1.3877x; 1.0757x over previous
//
#include <hip/hip_runtime.h>
#include <math.h>

#define N_NODES   80000
#define NU_NODES  40000
#define E_EDGES   1280000
#define B_PAIRS   8192
#define NEG_SLOPE 0.2f

// ---------------- CSR build ----------------

__global__ void hist_kernel(const int* __restrict__ dst, int* __restrict__ counts, int E) {
    int e = blockIdx.x * 256 + threadIdx.x;
    if (e < E) atomicAdd(&counts[dst[e]], 1);
}

__global__ void scan_blocks_kernel(const int* __restrict__ counts, int* __restrict__ row_ptr,
                                   int* __restrict__ bsums, int n) {
    __shared__ int tmp[1024];
    int gid = blockIdx.x * 1024 + threadIdx.x;
    int v = (gid < n) ? counts[gid] : 0;
    tmp[threadIdx.x] = v;
    __syncthreads();
    for (int off = 1; off < 1024; off <<= 1) {
        int t = (threadIdx.x >= off) ? tmp[threadIdx.x - off] : 0;
        __syncthreads();
        tmp[threadIdx.x] += t;
        __syncthreads();
    }
    if (gid < n) row_ptr[gid + 1] = tmp[threadIdx.x];
    if (threadIdx.x == 1023) bsums[blockIdx.x] = tmp[1023];
}

__global__ void scan_sums_kernel(int* bsums, int nb) {
    __shared__ int tmp[256];
    int v = (threadIdx.x < nb) ? bsums[threadIdx.x] : 0;
    tmp[threadIdx.x] = v;
    __syncthreads();
    for (int off = 1; off < 256; off <<= 1) {
        int t = (threadIdx.x >= off) ? tmp[threadIdx.x - off] : 0;
        __syncthreads();
        tmp[threadIdx.x] += t;
        __syncthreads();
    }
    if (threadIdx.x < nb) bsums[threadIdx.x] = tmp[threadIdx.x] - v;  // exclusive
}

__global__ void add_offsets_kernel(int* row_ptr, const int* __restrict__ bsums, int n) {
    int gid = blockIdx.x * 256 + threadIdx.x;
    if (gid < n) row_ptr[gid + 1] += bsums[gid >> 10];
    if (gid == 0) row_ptr[0] = 0;
}

__global__ void scatter_kernel(const int* __restrict__ srcArr, const int* __restrict__ dstArr,
                               const int* __restrict__ row_ptr, int* __restrict__ fill,
                               int* __restrict__ src_sorted, int E) {
    int e = blockIdx.x * 256 + threadIdx.x;
    if (e < E) {
        int d = dstArr[e];
        int pos = atomicAdd(&fill[d], 1);
        src_sorted[row_ptr[d] + pos] = srcArr[e];
    }
}

// ---------------- GEMM: [M,K] @ [K,128] -> [M,128], register-tiled ----------------
// 128x128 block tile, 256 threads, 8x8 micro-tile per thread, K chunked by 32.
// A split across two base pointers at row `split` (Gu/Gi concat), handled per row.
// As is stored k-major (transposed) with XOR swizzle to limit staging-write conflicts
// while keeping 4-row groups contiguous for b128 reads.

#define FMA4(dst, av, bv)                 \
    dst.x = fmaf(av, bv.x, dst.x);        \
    dst.y = fmaf(av, bv.y, dst.y);        \
    dst.z = fmaf(av, bv.z, dst.z);        \
    dst.w = fmaf(av, bv.w, dst.w);

template <int K>
__global__ __launch_bounds__(256, 4) void gemm_kernel(const float* __restrict__ A0,
                                                      const float* __restrict__ A1, int split,
                                                      const float* __restrict__ W,
                                                      float* __restrict__ out) {
    __shared__ float As[32][128];  // As[k][row ^ ((k&7)<<2)] = A[row0+row][k0+k]
    __shared__ float Bs[32][128];  // Bs[k][col]              = W[k0+k][col]
    const int tid  = threadIdx.x;
    const int row0 = blockIdx.x * 128;
    const int tc   = tid & 15;  // col group: cols tc*4+{0..3} and 64+tc*4+{0..3}
    const int tr   = tid >> 4;  // row group: rows tr*4+{0..3} and 64+tr*4+{0..3}

    float4 acc[2][2][4];
#pragma unroll
    for (int a = 0; a < 2; ++a)
#pragma unroll
        for (int b = 0; b < 2; ++b)
#pragma unroll
            for (int i = 0; i < 4; ++i) acc[a][b][i] = make_float4(0.f, 0.f, 0.f, 0.f);

#pragma unroll 1
    for (int k0 = 0; k0 < K; k0 += 32) {
        // stage B (W already k-major): 32x128 floats, coalesced float4
#pragma unroll
        for (int p = 0; p < 4; ++p) {
            int idx = tid + p * 256;  // 0..1023
            int r = idx >> 5, c4 = idx & 31;
            *(float4*)&Bs[r][c4 * 4] = *(const float4*)&W[(size_t)(k0 + r) * 128 + c4 * 4];
        }
        // stage A transposed with swizzle
#pragma unroll
        for (int p = 0; p < 4; ++p) {
            int idx = tid + p * 256;   // 0..1023
            int r = idx >> 3, kq = idx & 7;  // r 0..127, kq 0..7
            int grow = row0 + r;
            const float* ap =
                (grow < split) ? (A0 + (size_t)grow * K) : (A1 + (size_t)(grow - split) * K);
            float4 v = *(const float4*)&ap[k0 + kq * 4];
            int kk = kq * 4;
            As[kk + 0][r ^ (((kk + 0) & 7) << 2)] = v.x;
            As[kk + 1][r ^ (((kk + 1) & 7) << 2)] = v.y;
            As[kk + 2][r ^ (((kk + 2) & 7) << 2)] = v.z;
            As[kk + 3][r ^ (((kk + 3) & 7) << 2)] = v.w;
        }
        __syncthreads();
#pragma unroll
        for (int k = 0; k < 32; ++k) {
            int sw = (k & 7) << 2;
            float4 a0 = *(const float4*)&As[k][(tr * 4) ^ sw];
            float4 a1 = *(const float4*)&As[k][(64 + tr * 4) ^ sw];
            float4 b0 = *(const float4*)&Bs[k][tc * 4];
            float4 b1 = *(const float4*)&Bs[k][64 + tc * 4];
#pragma unroll
            for (int i = 0; i < 4; ++i) {
                float ar0 = ((const float*)&a0)[i];
                float ar1 = ((const float*)&a1)[i];
                FMA4(acc[0][0][i], ar0, b0);
                FMA4(acc[0][1][i], ar0, b1);
                FMA4(acc[1][0][i], ar1, b0);
                FMA4(acc[1][1][i], ar1, b1);
            }
        }
        __syncthreads();
    }

#pragma unroll
    for (int rh = 0; rh < 2; ++rh)
#pragma unroll
        for (int i = 0; i < 4; ++i) {
            int row = row0 + rh * 64 + tr * 4 + i;
            float4* op = (float4*)&out[(size_t)row * 128];
            op[tc]      = acc[rh][0][i];
            op[16 + tc] = acc[rh][1][i];
        }
}

// ---------------- attention dots: one wave per node, both heads ----------------

__global__ __launch_bounds__(256) void att_dots_kernel(const float* __restrict__ h,
                                const float* __restrict__ att_s,
                                const float* __restrict__ att_d, float* __restrict__ a_s,
                                float* __restrict__ a_d, int N) {
    int w    = blockIdx.x * 4 + (threadIdx.x >> 6);
    int lane = threadIdx.x & 63;
    if (w >= N) return;
    float2 v  = *(const float2*)(h + (size_t)w * 128 + lane * 2);
    float2 cs = *(const float2*)(att_s + lane * 2);
    float2 cd = *(const float2*)(att_d + lane * 2);
    float s = v.x * cs.x + v.y * cs.y;
    float d = v.x * cd.x + v.y * cd.y;
    for (int o = 16; o; o >>= 1) { s += __shfl_xor(s, o); d += __shfl_xor(d, o); }
    if ((lane & 31) == 0) {
        int hh = lane >> 5;
        a_s[w * 2 + hh] = s;
        a_d[w * 2 + hh] = d;
    }
}

// ---------------- GAT aggregation: one WAVE per dst node, both heads ----------------
// lane covers channels (2*lane, 2*lane+1) of the concat [H*C]=128; head = lane>>5.

template <bool CONCAT>
__global__ __launch_bounds__(256) void gat_agg_kernel(const float* __restrict__ h,
        const int* __restrict__ row_ptr, const int* __restrict__ src_sorted,
        const float* __restrict__ a_s, const float* __restrict__ a_d,
        const float* __restrict__ bias, float* __restrict__ out) {
    __shared__ int   s_idx[4][64];
    __shared__ float s_w[4][64][2];
    int wid   = threadIdx.x >> 6;
    int lane  = threadIdx.x & 63;
    int dnode = blockIdx.x * 4 + wid;
    if (dnode >= N_NODES) return;
    int start = row_ptr[dnode], end = row_ptr[dnode + 1];
    int deg = end - start;
    float2 ad = *(const float2*)(a_d + dnode * 2);
    int hh = lane >> 5;
    float2 acc = {0.f, 0.f};
    float den0 = 0.f, den1 = 0.f;

    if (deg <= 64) {  // fast path: edge data stays in registers across max-reduce
        float v0 = -INFINITY, v1 = -INFINITY;
        int s = 0;
        if (lane < deg) {
            s = src_sorted[start + lane];
            float2 as = *(const float2*)(a_s + s * 2);
            v0 = as.x + ad.x; v0 = v0 > 0.f ? v0 : NEG_SLOPE * v0;
            v1 = as.y + ad.y; v1 = v1 > 0.f ? v1 : NEG_SLOPE * v1;
        }
        float m0 = v0, m1 = v1;
        for (int o = 32; o; o >>= 1) {
            m0 = fmaxf(m0, __shfl_xor(m0, o));
            m1 = fmaxf(m1, __shfl_xor(m1, o));
        }
        if (lane < deg) {
            float w0 = __expf(v0 - m0), w1 = __expf(v1 - m1);
            den0 = w0; den1 = w1;
            s_idx[wid][lane] = s;
            s_w[wid][lane][0] = w0;
            s_w[wid][lane][1] = w1;
        }
        for (int j = 0; j < deg; ++j) {
            int  si = s_idx[wid][j];
            float w = s_w[wid][j][hh];
            float2 v = *(const float2*)(h + (size_t)si * 128 + lane * 2);
            acc.x = fmaf(w, v.x, acc.x);
            acc.y = fmaf(w, v.y, acc.y);
        }
    } else {  // general path (vanishingly rare for Poisson(16) degrees)
        float m0 = -INFINITY, m1 = -INFINITY;
        for (int k = start + lane; k < end; k += 64) {
            int s = src_sorted[k];
            float2 as = *(const float2*)(a_s + s * 2);
            float v0 = as.x + ad.x; v0 = v0 > 0.f ? v0 : NEG_SLOPE * v0;
            float v1 = as.y + ad.y; v1 = v1 > 0.f ? v1 : NEG_SLOPE * v1;
            m0 = fmaxf(m0, v0); m1 = fmaxf(m1, v1);
        }
        for (int o = 32; o; o >>= 1) {
            m0 = fmaxf(m0, __shfl_xor(m0, o));
            m1 = fmaxf(m1, __shfl_xor(m1, o));
        }
        for (int c0 = start; c0 < end; c0 += 64) {
            int len = min(64, end - c0);
            if (lane < len) {
                int s = src_sorted[c0 + lane];
                float2 as = *(const float2*)(a_s + s * 2);
                float v0 = as.x + ad.x; v0 = v0 > 0.f ? v0 : NEG_SLOPE * v0;
                float v1 = as.y + ad.y; v1 = v1 > 0.f ? v1 : NEG_SLOPE * v1;
                float w0 = __expf(v0 - m0), w1 = __expf(v1 - m1);
                den0 += w0; den1 += w1;
                s_idx[wid][lane] = s;
                s_w[wid][lane][0] = w0;
                s_w[wid][lane][1] = w1;
            }
            for (int j = 0; j < len; ++j) {
                int  si = s_idx[wid][j];
                float w = s_w[wid][j][hh];
                float2 v = *(const float2*)(h + (size_t)si * 128 + lane * 2);
                acc.x = fmaf(w, v.x, acc.x);
                acc.y = fmaf(w, v.y, acc.y);
            }
        }
    }

    for (int o = 32; o; o >>= 1) {
        den0 += __shfl_xor(den0, o);
        den1 += __shfl_xor(den1, o);
    }
    float inv = 1.f / ((hh ? den1 : den0) + 1e-16f);
    float2 r = {acc.x * inv, acc.y * inv};

    if (CONCAT) {
        float2 b = *(const float2*)(bias + lane * 2);
        float2 o2 = {r.x + b.x, r.y + b.y};
        *(float2*)(out + (size_t)dnode * 128 + lane * 2) = o2;
    } else {
        float ox = __shfl_xor(r.x, 32);
        float oy = __shfl_xor(r.y, 32);
        if (lane < 32) {
            float2 b = *(const float2*)(bias + lane * 2);
            float2 o2 = {0.5f * (r.x + ox) + b.x, 0.5f * (r.y + oy) + b.y};
            *(float2*)(out + (size_t)dnode * 64 + lane * 2) = o2;
        }
    }
}

// ---------------- final pair dot ----------------

__global__ void pair_dot_kernel(const float* __restrict__ emb, const int* __restrict__ ui,
                                const int* __restrict__ ii, float* __restrict__ out, int B) {
    int w    = blockIdx.x * 4 + (threadIdx.x >> 6);
    int lane = threadIdx.x & 63;
    if (w >= B) return;
    float a = emb[(size_t)ui[w] * 64 + lane];
    float b = emb[(size_t)(NU_NODES + ii[w]) * 64 + lane];
    float p = a * b;
    for (int o = 32; o; o >>= 1) p += __shfl_xor(p, o);
    if (lane == 0) out[w] = p;
}

extern "C" void kernel_launch(void* const* d_in, const int* in_sizes, int n_in,
                              void* d_out, int out_size, void* d_ws, size_t ws_size,
                              hipStream_t stream) {
    const float* Gu       = (const float*)d_in[0];
    const float* Gi       = (const float*)d_in[1];
    const float* W0       = (const float*)d_in[2];
    const float* att_src0 = (const float*)d_in[3];
    const float* att_dst0 = (const float*)d_in[4];
    const float* b0       = (const float*)d_in[5];
    const float* W1       = (const float*)d_in[6];
    const float* att_src1 = (const float*)d_in[7];
    const float* att_dst1 = (const float*)d_in[8];
    const float* b1       = (const float*)d_in[9];
    const int* edge_index = (const int*)d_in[10];
    const int* user_idx   = (const int*)d_in[11];
    const int* item_idx   = (const int*)d_in[12];
    float* outp           = (float*)d_out;

    const int N = N_NODES, E = E_EDGES;
    char* wsp = (char*)d_ws;
    auto alloc = [&](size_t bytes) {
        void* p = wsp;
        wsp += (bytes + 255) & ~(size_t)255;
        return p;
    };
    float* emb = (float*)alloc((size_t)N * 64 * 4);   // final embeddings
    float* h   = (float*)alloc((size_t)N * 128 * 4);  // h0, then h1
    float* x1  = (float*)alloc((size_t)N * 128 * 4);  // layer0 output
    float* a_s = (float*)alloc((size_t)N * 2 * 4);
    float* a_d = (float*)alloc((size_t)N * 2 * 4);
    int* row_ptr    = (int*)alloc((size_t)(N + 1) * 4);
    int* counts     = (int*)alloc((size_t)N * 4);
    int* fill       = (int*)alloc((size_t)N * 4);
    int* bsums      = (int*)alloc(256 * 4);
    int* src_sorted = (int*)alloc((size_t)E * 4);

    const int* esrc = edge_index;
    const int* edst = edge_index + E;

    // CSR by dst
    hipMemsetAsync(counts, 0, (size_t)N * 4, stream);
    hipMemsetAsync(fill, 0, (size_t)N * 4, stream);
    hist_kernel<<<E / 256, 256, 0, stream>>>(edst, counts, E);
    int nb = (N + 1023) / 1024;
    scan_blocks_kernel<<<nb, 1024, 0, stream>>>(counts, row_ptr, bsums, N);
    scan_sums_kernel<<<1, 256, 0, stream>>>(bsums, nb);
    add_offsets_kernel<<<(N + 255) / 256, 256, 0, stream>>>(row_ptr, bsums, N);
    scatter_kernel<<<E / 256, 256, 0, stream>>>(esrc, edst, row_ptr, fill, src_sorted, E);

    // layer 0  (A read directly from Gu/Gi, no concat copy)
    gemm_kernel<64><<<N / 128, 256, 0, stream>>>(Gu, Gi, NU_NODES, W0, h);
    att_dots_kernel<<<(N + 3) / 4, 256, 0, stream>>>(h, att_src0, att_dst0, a_s, a_d, N);
    gat_agg_kernel<true><<<(N + 3) / 4, 256, 0, stream>>>(h, row_ptr, src_sorted, a_s, a_d, b0, x1);

    // layer 1
    gemm_kernel<128><<<N / 128, 256, 0, stream>>>(x1, x1, N, W1, h);
    att_dots_kernel<<<(N + 3) / 4, 256, 0, stream>>>(h, att_src1, att_dst1, a_s, a_d, N);
    gat_agg_kernel<false><<<(N + 3) / 4, 256, 0, stream>>>(h, row_ptr, src_sorted, a_s, a_d, b1, emb);

    // final dot
    pair_dot_kernel<<<B_PAIRS / 4, 256, 0, stream>>>(emb, user_idx, item_idx, outp, B_PAIRS);
}

// Round 4
// 442.478 us; speedup vs baseline: 1.3901x; 1.0018x over previous
//
#include <hip/hip_runtime.h>
#include <hip/hip_fp16.h>
#include <math.h>

#define N_NODES   80000
#define NU_NODES  40000
#define E_EDGES   1280000
#define B_PAIRS   8192
#define NEG_SLOPE 0.2f

// ---------------- CSR build ----------------

__global__ void hist_kernel(const int* __restrict__ dst, int* __restrict__ counts, int E) {
    int e = blockIdx.x * 256 + threadIdx.x;
    if (e < E) atomicAdd(&counts[dst[e]], 1);
}

__global__ void scan_blocks_kernel(const int* __restrict__ counts, int* __restrict__ row_ptr,
                                   int* __restrict__ bsums, int n) {
    __shared__ int tmp[1024];
    int gid = blockIdx.x * 1024 + threadIdx.x;
    int v = (gid < n) ? counts[gid] : 0;
    tmp[threadIdx.x] = v;
    __syncthreads();
    for (int off = 1; off < 1024; off <<= 1) {
        int t = (threadIdx.x >= off) ? tmp[threadIdx.x - off] : 0;
        __syncthreads();
        tmp[threadIdx.x] += t;
        __syncthreads();
    }
    if (gid < n) row_ptr[gid + 1] = tmp[threadIdx.x];
    if (threadIdx.x == 1023) bsums[blockIdx.x] = tmp[1023];
}

__global__ void scan_sums_kernel(int* bsums, int nb) {
    __shared__ int tmp[256];
    int v = (threadIdx.x < nb) ? bsums[threadIdx.x] : 0;
    tmp[threadIdx.x] = v;
    __syncthreads();
    for (int off = 1; off < 256; off <<= 1) {
        int t = (threadIdx.x >= off) ? tmp[threadIdx.x - off] : 0;
        __syncthreads();
        tmp[threadIdx.x] += t;
        __syncthreads();
    }
    if (threadIdx.x < nb) bsums[threadIdx.x] = tmp[threadIdx.x] - v;  // exclusive
}

__global__ void add_offsets_kernel(int* row_ptr, const int* __restrict__ bsums, int n) {
    int gid = blockIdx.x * 256 + threadIdx.x;
    if (gid < n) row_ptr[gid + 1] += bsums[gid >> 10];
    if (gid == 0) row_ptr[0] = 0;
}

__global__ void scatter_kernel(const int* __restrict__ srcArr, const int* __restrict__ dstArr,
                               const int* __restrict__ row_ptr, int* __restrict__ fill,
                               int* __restrict__ src_sorted, int E) {
    int e = blockIdx.x * 256 + threadIdx.x;
    if (e < E) {
        int d = dstArr[e];
        int pos = atomicAdd(&fill[d], 1);
        src_sorted[row_ptr[d] + pos] = srcArr[e];
    }
}

// ---------------- GEMM + fused attention-dot epilogue ----------------
// [M,K] @ [K,128] -> h (fp16) and a_s/a_d (f32 dots vs att vectors).
// 128x128 block tile, 256 threads, 8x8 micro-tile, K chunked by 32.

#define FMA4(dst, av, bv)                 \
    dst.x = fmaf(av, bv.x, dst.x);        \
    dst.y = fmaf(av, bv.y, dst.y);        \
    dst.z = fmaf(av, bv.z, dst.z);        \
    dst.w = fmaf(av, bv.w, dst.w);

#define DOT4(a, b) (a.x * b.x + a.y * b.y + a.z * b.z + a.w * b.w)

struct alignas(8) H4 { __half2 a, b; };

template <int K>
__global__ __launch_bounds__(256, 4) void gemm_kernel(const float* __restrict__ A0,
                                                      const float* __restrict__ A1, int split,
                                                      const float* __restrict__ W,
                                                      const float* __restrict__ attS,
                                                      const float* __restrict__ attD,
                                                      __half* __restrict__ hh,
                                                      float* __restrict__ a_s,
                                                      float* __restrict__ a_d) {
    __shared__ float As[32][128];  // As[k][row ^ ((k&7)<<2)] = A[row0+row][k0+k]
    __shared__ float Bs[32][128];  // Bs[k][col]              = W[k0+k][col]
    const int tid  = threadIdx.x;
    const int row0 = blockIdx.x * 128;
    const int tc   = tid & 15;  // col group: cols tc*4+{0..3} and 64+tc*4+{0..3}
    const int tr   = tid >> 4;  // row group: rows tr*4+{0..3} and 64+tr*4+{0..3}

    float4 acc[2][2][4];
#pragma unroll
    for (int a = 0; a < 2; ++a)
#pragma unroll
        for (int b = 0; b < 2; ++b)
#pragma unroll
            for (int i = 0; i < 4; ++i) acc[a][b][i] = make_float4(0.f, 0.f, 0.f, 0.f);

#pragma unroll 1
    for (int k0 = 0; k0 < K; k0 += 32) {
#pragma unroll
        for (int p = 0; p < 4; ++p) {
            int idx = tid + p * 256;
            int r = idx >> 5, c4 = idx & 31;
            *(float4*)&Bs[r][c4 * 4] = *(const float4*)&W[(size_t)(k0 + r) * 128 + c4 * 4];
        }
#pragma unroll
        for (int p = 0; p < 4; ++p) {
            int idx = tid + p * 256;
            int r = idx >> 3, kq = idx & 7;
            int grow = row0 + r;
            const float* ap =
                (grow < split) ? (A0 + (size_t)grow * K) : (A1 + (size_t)(grow - split) * K);
            float4 v = *(const float4*)&ap[k0 + kq * 4];
            int kk = kq * 4;
            As[kk + 0][r ^ (((kk + 0) & 7) << 2)] = v.x;
            As[kk + 1][r ^ (((kk + 1) & 7) << 2)] = v.y;
            As[kk + 2][r ^ (((kk + 2) & 7) << 2)] = v.z;
            As[kk + 3][r ^ (((kk + 3) & 7) << 2)] = v.w;
        }
        __syncthreads();
#pragma unroll
        for (int k = 0; k < 32; ++k) {
            int sw = (k & 7) << 2;
            float4 a0 = *(const float4*)&As[k][(tr * 4) ^ sw];
            float4 a1 = *(const float4*)&As[k][(64 + tr * 4) ^ sw];
            float4 b0 = *(const float4*)&Bs[k][tc * 4];
            float4 b1 = *(const float4*)&Bs[k][64 + tc * 4];
#pragma unroll
            for (int i = 0; i < 4; ++i) {
                float ar0 = ((const float*)&a0)[i];
                float ar1 = ((const float*)&a1)[i];
                FMA4(acc[0][0][i], ar0, b0);
                FMA4(acc[0][1][i], ar0, b1);
                FMA4(acc[1][0][i], ar1, b0);
                FMA4(acc[1][1][i], ar1, b1);
            }
        }
        __syncthreads();
    }

    // epilogue: fp16 h store + attention dots (16-lane reduce; lanes sharing tr
    // are consecutive, so shfl_xor {1,2,4,8} reduces across the row's owners)
    const float4 vs0 = *(const float4*)&attS[tc * 4];
    const float4 vs1 = *(const float4*)&attS[64 + tc * 4];
    const float4 vd0 = *(const float4*)&attD[tc * 4];
    const float4 vd1 = *(const float4*)&attD[64 + tc * 4];
#pragma unroll
    for (int rh = 0; rh < 2; ++rh)
#pragma unroll
        for (int i = 0; i < 4; ++i) {
            int row = row0 + rh * 64 + tr * 4 + i;
            float4 a0 = acc[rh][0][i];
            float4 a1 = acc[rh][1][i];
            H4 h0, h1;
            h0.a = __float22half2_rn(make_float2(a0.x, a0.y));
            h0.b = __float22half2_rn(make_float2(a0.z, a0.w));
            h1.a = __float22half2_rn(make_float2(a1.x, a1.y));
            h1.b = __float22half2_rn(make_float2(a1.z, a1.w));
            *(H4*)(hh + (size_t)row * 128 + tc * 4)      = h0;
            *(H4*)(hh + (size_t)row * 128 + 64 + tc * 4) = h1;
            float s0 = DOT4(a0, vs0), s1 = DOT4(a1, vs1);
            float d0 = DOT4(a0, vd0), d1 = DOT4(a1, vd1);
#pragma unroll
            for (int o = 1; o < 16; o <<= 1) {
                s0 += __shfl_xor(s0, o);
                s1 += __shfl_xor(s1, o);
                d0 += __shfl_xor(d0, o);
                d1 += __shfl_xor(d1, o);
            }
            if (tc == 0) {
                *(float2*)&a_s[row * 2] = make_float2(s0, s1);
                *(float2*)&a_d[row * 2] = make_float2(d0, d1);
            }
        }
}

// ---------------- GAT aggregation: one WAVE per dst node, both heads ----------------
// lane covers channels (2*lane, 2*lane+1); head = lane>>5. h is fp16 (256B/row).

template <bool CONCAT>
__global__ __launch_bounds__(256) void gat_agg_kernel(const __half* __restrict__ hh,
        const int* __restrict__ row_ptr, const int* __restrict__ src_sorted,
        const float* __restrict__ a_s, const float* __restrict__ a_d,
        const float* __restrict__ bias, float* __restrict__ out) {
    __shared__ int   s_idx[4][64];
    __shared__ float s_w[4][64][2];
    int wid   = threadIdx.x >> 6;
    int lane  = threadIdx.x & 63;
    int dnode = blockIdx.x * 4 + wid;
    if (dnode >= N_NODES) return;
    int start = row_ptr[dnode], end = row_ptr[dnode + 1];
    int deg = end - start;
    float2 ad = *(const float2*)(a_d + dnode * 2);
    int hh_head = lane >> 5;
    float2 acc = {0.f, 0.f};
    float den0 = 0.f, den1 = 0.f;
    const __half2* h2 = (const __half2*)hh;

    if (deg <= 64) {  // fast path
        float v0 = -INFINITY, v1 = -INFINITY;
        int s = 0;
        if (lane < deg) {
            s = src_sorted[start + lane];
            float2 as = *(const float2*)(a_s + s * 2);
            v0 = as.x + ad.x; v0 = v0 > 0.f ? v0 : NEG_SLOPE * v0;
            v1 = as.y + ad.y; v1 = v1 > 0.f ? v1 : NEG_SLOPE * v1;
        }
        float m0 = v0, m1 = v1;
        for (int o = 32; o; o >>= 1) {
            m0 = fmaxf(m0, __shfl_xor(m0, o));
            m1 = fmaxf(m1, __shfl_xor(m1, o));
        }
        if (lane < deg) {
            float w0 = __expf(v0 - m0), w1 = __expf(v1 - m1);
            den0 = w0; den1 = w1;
            s_idx[wid][lane] = s;
            s_w[wid][lane][0] = w0;
            s_w[wid][lane][1] = w1;
        }
        for (int j = 0; j < deg; ++j) {
            int  si = s_idx[wid][j];
            float w = s_w[wid][j][hh_head];
            float2 v = __half22float2(h2[(size_t)si * 64 + lane]);
            acc.x = fmaf(w, v.x, acc.x);
            acc.y = fmaf(w, v.y, acc.y);
        }
    } else {  // general path (rare for Poisson(16))
        float m0 = -INFINITY, m1 = -INFINITY;
        for (int k = start + lane; k < end; k += 64) {
            int s = src_sorted[k];
            float2 as = *(const float2*)(a_s + s * 2);
            float v0 = as.x + ad.x; v0 = v0 > 0.f ? v0 : NEG_SLOPE * v0;
            float v1 = as.y + ad.y; v1 = v1 > 0.f ? v1 : NEG_SLOPE * v1;
            m0 = fmaxf(m0, v0); m1 = fmaxf(m1, v1);
        }
        for (int o = 32; o; o >>= 1) {
            m0 = fmaxf(m0, __shfl_xor(m0, o));
            m1 = fmaxf(m1, __shfl_xor(m1, o));
        }
        for (int c0 = start; c0 < end; c0 += 64) {
            int len = min(64, end - c0);
            if (lane < len) {
                int s = src_sorted[c0 + lane];
                float2 as = *(const float2*)(a_s + s * 2);
                float v0 = as.x + ad.x; v0 = v0 > 0.f ? v0 : NEG_SLOPE * v0;
                float v1 = as.y + ad.y; v1 = v1 > 0.f ? v1 : NEG_SLOPE * v1;
                float w0 = __expf(v0 - m0), w1 = __expf(v1 - m1);
                den0 += w0; den1 += w1;
                s_idx[wid][lane] = s;
                s_w[wid][lane][0] = w0;
                s_w[wid][lane][1] = w1;
            }
            for (int j = 0; j < len; ++j) {
                int  si = s_idx[wid][j];
                float w = s_w[wid][j][hh_head];
                float2 v = __half22float2(h2[(size_t)si * 64 + lane]);
                acc.x = fmaf(w, v.x, acc.x);
                acc.y = fmaf(w, v.y, acc.y);
            }
        }
    }

    for (int o = 32; o; o >>= 1) {
        den0 += __shfl_xor(den0, o);
        den1 += __shfl_xor(den1, o);
    }
    float inv = 1.f / ((hh_head ? den1 : den0) + 1e-16f);
    float2 r = {acc.x * inv, acc.y * inv};

    if (CONCAT) {
        float2 b = *(const float2*)(bias + lane * 2);
        float2 o2 = {r.x + b.x, r.y + b.y};
        *(float2*)(out + (size_t)dnode * 128 + lane * 2) = o2;
    } else {
        float ox = __shfl_xor(r.x, 32);
        float oy = __shfl_xor(r.y, 32);
        if (lane < 32) {
            float2 b = *(const float2*)(bias + lane * 2);
            float2 o2 = {0.5f * (r.x + ox) + b.x, 0.5f * (r.y + oy) + b.y};
            *(float2*)(out + (size_t)dnode * 64 + lane * 2) = o2;
        }
    }
}

// ---------------- final pair dot ----------------

__global__ void pair_dot_kernel(const float* __restrict__ emb, const int* __restrict__ ui,
                                const int* __restrict__ ii, float* __restrict__ out, int B) {
    int w    = blockIdx.x * 4 + (threadIdx.x >> 6);
    int lane = threadIdx.x & 63;
    if (w >= B) return;
    float a = emb[(size_t)ui[w] * 64 + lane];
    float b = emb[(size_t)(NU_NODES + ii[w]) * 64 + lane];
    float p = a * b;
    for (int o = 32; o; o >>= 1) p += __shfl_xor(p, o);
    if (lane == 0) out[w] = p;
}

extern "C" void kernel_launch(void* const* d_in, const int* in_sizes, int n_in,
                              void* d_out, int out_size, void* d_ws, size_t ws_size,
                              hipStream_t stream) {
    const float* Gu       = (const float*)d_in[0];
    const float* Gi       = (const float*)d_in[1];
    const float* W0       = (const float*)d_in[2];
    const float* att_src0 = (const float*)d_in[3];
    const float* att_dst0 = (const float*)d_in[4];
    const float* b0       = (const float*)d_in[5];
    const float* W1       = (const float*)d_in[6];
    const float* att_src1 = (const float*)d_in[7];
    const float* att_dst1 = (const float*)d_in[8];
    const float* b1       = (const float*)d_in[9];
    const int* edge_index = (const int*)d_in[10];
    const int* user_idx   = (const int*)d_in[11];
    const int* item_idx   = (const int*)d_in[12];
    float* outp           = (float*)d_out;

    const int N = N_NODES, E = E_EDGES;
    char* wsp = (char*)d_ws;
    auto alloc = [&](size_t bytes) {
        void* p = wsp;
        wsp += (bytes + 255) & ~(size_t)255;
        return p;
    };
    float*  emb = (float*)alloc((size_t)N * 64 * 4);    // final embeddings
    __half* hh  = (__half*)alloc((size_t)N * 128 * 2);  // fp16 h (both layers)
    float*  x1  = (float*)alloc((size_t)N * 128 * 4);   // layer0 output (f32)
    float*  a_s = (float*)alloc((size_t)N * 2 * 4);
    float*  a_d = (float*)alloc((size_t)N * 2 * 4);
    int* row_ptr    = (int*)alloc((size_t)(N + 1) * 4);
    int* counts     = (int*)alloc((size_t)N * 4);
    int* fill       = (int*)alloc((size_t)N * 4);
    int* bsums      = (int*)alloc(256 * 4);
    int* src_sorted = (int*)alloc((size_t)E * 4);

    const int* esrc = edge_index;
    const int* edst = edge_index + E;

    // CSR by dst
    hipMemsetAsync(counts, 0, (size_t)N * 4, stream);
    hipMemsetAsync(fill, 0, (size_t)N * 4, stream);
    hist_kernel<<<E / 256, 256, 0, stream>>>(edst, counts, E);
    int nb = (N + 1023) / 1024;
    scan_blocks_kernel<<<nb, 1024, 0, stream>>>(counts, row_ptr, bsums, N);
    scan_sums_kernel<<<1, 256, 0, stream>>>(bsums, nb);
    add_offsets_kernel<<<(N + 255) / 256, 256, 0, stream>>>(row_ptr, bsums, N);
    scatter_kernel<<<E / 256, 256, 0, stream>>>(esrc, edst, row_ptr, fill, src_sorted, E);

    // layer 0 (A read directly from Gu/Gi; h fp16 + att dots fused)
    gemm_kernel<64><<<N / 128, 256, 0, stream>>>(Gu, Gi, NU_NODES, W0, att_src0, att_dst0,
                                                 hh, a_s, a_d);
    gat_agg_kernel<true><<<(N + 3) / 4, 256, 0, stream>>>(hh, row_ptr, src_sorted, a_s, a_d,
                                                          b0, x1);

    // layer 1
    gemm_kernel<128><<<N / 128, 256, 0, stream>>>(x1, x1, N, W1, att_src1, att_dst1,
                                                  hh, a_s, a_d);
    gat_agg_kernel<false><<<(N + 3) / 4, 256, 0, stream>>>(hh, row_ptr, src_sorted, a_s, a_d,
                                                           b1, emb);

    // final dot
    pair_dot_kernel<<<B_PAIRS / 4, 256, 0, stream>>>(emb, user_idx, item_idx, outp, B_PAIRS);
}

// Round 5
// 348.780 us; speedup vs baseline: 1.7636x; 1.2686x over previous
//
#include <hip/hip_runtime.h>
#include <hip/hip_fp16.h>
#include <math.h>

#define N_NODES   80000
#define NU_NODES  40000
#define E_EDGES   1280000
#define B_PAIRS   8192
#define NEG_SLOPE 0.2f

// ---------------- CSR build ----------------

__global__ void hist_kernel(const int* __restrict__ dst, int* __restrict__ counts, int E) {
    int e = blockIdx.x * 256 + threadIdx.x;
    if (e < E) atomicAdd(&counts[dst[e]], 1);
}

__global__ void scan_blocks_kernel(const int* __restrict__ counts, int* __restrict__ row_ptr,
                                   int* __restrict__ bsums, int n) {
    __shared__ int tmp[1024];
    int gid = blockIdx.x * 1024 + threadIdx.x;
    int v = (gid < n) ? counts[gid] : 0;
    tmp[threadIdx.x] = v;
    __syncthreads();
    for (int off = 1; off < 1024; off <<= 1) {
        int t = (threadIdx.x >= off) ? tmp[threadIdx.x - off] : 0;
        __syncthreads();
        tmp[threadIdx.x] += t;
        __syncthreads();
    }
    if (gid < n) row_ptr[gid + 1] = tmp[threadIdx.x];
    if (threadIdx.x == 1023) bsums[blockIdx.x] = tmp[1023];
}

__global__ void scan_sums_kernel(int* bsums, int nb) {
    __shared__ int tmp[256];
    int v = (threadIdx.x < nb) ? bsums[threadIdx.x] : 0;
    tmp[threadIdx.x] = v;
    __syncthreads();
    for (int off = 1; off < 256; off <<= 1) {
        int t = (threadIdx.x >= off) ? tmp[threadIdx.x - off] : 0;
        __syncthreads();
        tmp[threadIdx.x] += t;
        __syncthreads();
    }
    if (threadIdx.x < nb) bsums[threadIdx.x] = tmp[threadIdx.x] - v;  // exclusive
}

__global__ void add_offsets_kernel(int* row_ptr, const int* __restrict__ bsums, int n) {
    int gid = blockIdx.x * 256 + threadIdx.x;
    if (gid < n) row_ptr[gid + 1] += bsums[gid >> 10];
    if (gid == 0) row_ptr[0] = 0;
}

__global__ void scatter_kernel(const int* __restrict__ srcArr, const int* __restrict__ dstArr,
                               const int* __restrict__ row_ptr, int* __restrict__ fill,
                               int* __restrict__ src_sorted, int E) {
    int e = blockIdx.x * 256 + threadIdx.x;
    if (e < E) {
        int d = dstArr[e];
        int pos = atomicAdd(&fill[d], 1);
        src_sorted[row_ptr[d] + pos] = srcArr[e];
    }
}

// ---------------- GEMM + fused attention-dot epilogue ----------------
// [M,K] @ [K,128] -> h (fp16) and a_s/a_d (f32 dots vs att vectors).
// 128x128 block tile, 256 threads, 8x8 micro-tile, K chunked by 32.
// Register-pressure discipline (R4 spilled): k-loop unroll 2 only, att
// vectors staged in LDS (read AFTER the last barrier, can't be hoisted),
// A staging pointers precomputed once.

#define FMA4(dst, av, bv)                 \
    dst.x = fmaf(av, bv.x, dst.x);        \
    dst.y = fmaf(av, bv.y, dst.y);        \
    dst.z = fmaf(av, bv.z, dst.z);        \
    dst.w = fmaf(av, bv.w, dst.w);

#define DOT4(a, b) (a.x * b.x + a.y * b.y + a.z * b.z + a.w * b.w)

struct alignas(8) H4 { __half2 a, b; };

template <int K>
__global__ __launch_bounds__(256, 4) void gemm_kernel(const float* __restrict__ A0,
                                                      const float* __restrict__ A1, int split,
                                                      const float* __restrict__ W,
                                                      const float* __restrict__ attS,
                                                      const float* __restrict__ attD,
                                                      __half* __restrict__ hh,
                                                      float* __restrict__ a_s,
                                                      float* __restrict__ a_d) {
    __shared__ float As[32][128];  // As[k][row ^ ((k&7)<<2)] = A[row0+row][k0+k]
    __shared__ float Bs[32][128];  // Bs[k][col]              = W[k0+k][col]
    __shared__ float attL[256];    // [0:128)=attS, [128:256)=attD
    const int tid  = threadIdx.x;
    const int row0 = blockIdx.x * 128;
    const int tc   = tid & 15;  // col group: cols tc*4+{0..3} and 64+tc*4+{0..3}
    const int tr   = tid >> 4;  // row group: rows tr*4+{0..3} and 64+tr*4+{0..3}

    attL[tid] = (tid < 128) ? attS[tid] : attD[tid - 128];

    // per-thread A staging pointers (4 fixed rows per thread across all k-chunks)
    const float* aptr[4];
#pragma unroll
    for (int p = 0; p < 4; ++p) {
        int idx  = tid + p * 256;
        int r    = idx >> 3;
        int grow = row0 + r;
        aptr[p] = (grow < split) ? (A0 + (size_t)grow * K) : (A1 + (size_t)(grow - split) * K);
    }

    float4 acc[2][2][4];
#pragma unroll
    for (int a = 0; a < 2; ++a)
#pragma unroll
        for (int b = 0; b < 2; ++b)
#pragma unroll
            for (int i = 0; i < 4; ++i) acc[a][b][i] = make_float4(0.f, 0.f, 0.f, 0.f);

#pragma unroll 1
    for (int k0 = 0; k0 < K; k0 += 32) {
#pragma unroll
        for (int p = 0; p < 4; ++p) {
            int idx = tid + p * 256;
            int r = idx >> 5, c4 = idx & 31;
            *(float4*)&Bs[r][c4 * 4] = *(const float4*)&W[(size_t)(k0 + r) * 128 + c4 * 4];
        }
#pragma unroll
        for (int p = 0; p < 4; ++p) {
            int idx = tid + p * 256;
            int r = idx >> 3, kq = idx & 7;
            float4 v = *(const float4*)&aptr[p][k0 + kq * 4];
            int kk = kq * 4;
            As[kk + 0][r ^ (((kk + 0) & 7) << 2)] = v.x;
            As[kk + 1][r ^ (((kk + 1) & 7) << 2)] = v.y;
            As[kk + 2][r ^ (((kk + 2) & 7) << 2)] = v.z;
            As[kk + 3][r ^ (((kk + 3) & 7) << 2)] = v.w;
        }
        __syncthreads();
#pragma unroll 2
        for (int k = 0; k < 32; ++k) {
            int sw = (k & 7) << 2;
            float4 a0 = *(const float4*)&As[k][(tr * 4) ^ sw];
            float4 a1 = *(const float4*)&As[k][(64 + tr * 4) ^ sw];
            float4 b0 = *(const float4*)&Bs[k][tc * 4];
            float4 b1 = *(const float4*)&Bs[k][64 + tc * 4];
#pragma unroll
            for (int i = 0; i < 4; ++i) {
                float ar0 = ((const float*)&a0)[i];
                float ar1 = ((const float*)&a1)[i];
                FMA4(acc[0][0][i], ar0, b0);
                FMA4(acc[0][1][i], ar0, b1);
                FMA4(acc[1][0][i], ar1, b0);
                FMA4(acc[1][1][i], ar1, b1);
            }
        }
        __syncthreads();
    }

    // epilogue: att vectors from LDS (post-barrier => not hoisted into the loop)
    const float4 vs0 = *(const float4*)&attL[tc * 4];
    const float4 vs1 = *(const float4*)&attL[64 + tc * 4];
    const float4 vd0 = *(const float4*)&attL[128 + tc * 4];
    const float4 vd1 = *(const float4*)&attL[192 + tc * 4];
#pragma unroll
    for (int rh = 0; rh < 2; ++rh)
#pragma unroll
        for (int i = 0; i < 4; ++i) {
            int row = row0 + rh * 64 + tr * 4 + i;
            float4 a0 = acc[rh][0][i];
            float4 a1 = acc[rh][1][i];
            H4 h0, h1;
            h0.a = __float22half2_rn(make_float2(a0.x, a0.y));
            h0.b = __float22half2_rn(make_float2(a0.z, a0.w));
            h1.a = __float22half2_rn(make_float2(a1.x, a1.y));
            h1.b = __float22half2_rn(make_float2(a1.z, a1.w));
            *(H4*)(hh + (size_t)row * 128 + tc * 4)      = h0;
            *(H4*)(hh + (size_t)row * 128 + 64 + tc * 4) = h1;
            float s0 = DOT4(a0, vs0), s1 = DOT4(a1, vs1);
            float d0 = DOT4(a0, vd0), d1 = DOT4(a1, vd1);
#pragma unroll
            for (int o = 1; o < 16; o <<= 1) {
                s0 += __shfl_xor(s0, o);
                s1 += __shfl_xor(s1, o);
                d0 += __shfl_xor(d0, o);
                d1 += __shfl_xor(d1, o);
            }
            if (tc == 0) {
                *(float2*)&a_s[row * 2] = make_float2(s0, s1);
                *(float2*)&a_d[row * 2] = make_float2(d0, d1);
            }
        }
}

// ---------------- GAT aggregation: one WAVE per dst node, both heads ----------------
// lane covers channels (2*lane, 2*lane+1); head = lane>>5. h is fp16 (256B/row).

template <bool CONCAT>
__global__ __launch_bounds__(256) void gat_agg_kernel(const __half* __restrict__ hh,
        const int* __restrict__ row_ptr, const int* __restrict__ src_sorted,
        const float* __restrict__ a_s, const float* __restrict__ a_d,
        const float* __restrict__ bias, float* __restrict__ out) {
    __shared__ int   s_idx[4][64];
    __shared__ float s_w[4][64][2];
    int wid   = threadIdx.x >> 6;
    int lane  = threadIdx.x & 63;
    int dnode = blockIdx.x * 4 + wid;
    if (dnode >= N_NODES) return;
    int start = row_ptr[dnode], end = row_ptr[dnode + 1];
    int deg = end - start;
    float2 ad = *(const float2*)(a_d + dnode * 2);
    int hh_head = lane >> 5;
    float2 acc = {0.f, 0.f};
    float den0 = 0.f, den1 = 0.f;
    const __half2* h2 = (const __half2*)hh;

    if (deg <= 64) {  // fast path
        float v0 = -INFINITY, v1 = -INFINITY;
        int s = 0;
        if (lane < deg) {
            s = src_sorted[start + lane];
            float2 as = *(const float2*)(a_s + s * 2);
            v0 = as.x + ad.x; v0 = v0 > 0.f ? v0 : NEG_SLOPE * v0;
            v1 = as.y + ad.y; v1 = v1 > 0.f ? v1 : NEG_SLOPE * v1;
        }
        float m0 = v0, m1 = v1;
        for (int o = 32; o; o >>= 1) {
            m0 = fmaxf(m0, __shfl_xor(m0, o));
            m1 = fmaxf(m1, __shfl_xor(m1, o));
        }
        if (lane < deg) {
            float w0 = __expf(v0 - m0), w1 = __expf(v1 - m1);
            den0 = w0; den1 = w1;
            s_idx[wid][lane] = s;
            s_w[wid][lane][0] = w0;
            s_w[wid][lane][1] = w1;
        }
        for (int j = 0; j < deg; ++j) {
            int  si = s_idx[wid][j];
            float w = s_w[wid][j][hh_head];
            float2 v = __half22float2(h2[(size_t)si * 64 + lane]);
            acc.x = fmaf(w, v.x, acc.x);
            acc.y = fmaf(w, v.y, acc.y);
        }
    } else {  // general path (rare for Poisson(16))
        float m0 = -INFINITY, m1 = -INFINITY;
        for (int k = start + lane; k < end; k += 64) {
            int s = src_sorted[k];
            float2 as = *(const float2*)(a_s + s * 2);
            float v0 = as.x + ad.x; v0 = v0 > 0.f ? v0 : NEG_SLOPE * v0;
            float v1 = as.y + ad.y; v1 = v1 > 0.f ? v1 : NEG_SLOPE * v1;
            m0 = fmaxf(m0, v0); m1 = fmaxf(m1, v1);
        }
        for (int o = 32; o; o >>= 1) {
            m0 = fmaxf(m0, __shfl_xor(m0, o));
            m1 = fmaxf(m1, __shfl_xor(m1, o));
        }
        for (int c0 = start; c0 < end; c0 += 64) {
            int len = min(64, end - c0);
            if (lane < len) {
                int s = src_sorted[c0 + lane];
                float2 as = *(const float2*)(a_s + s * 2);
                float v0 = as.x + ad.x; v0 = v0 > 0.f ? v0 : NEG_SLOPE * v0;
                float v1 = as.y + ad.y; v1 = v1 > 0.f ? v1 : NEG_SLOPE * v1;
                float w0 = __expf(v0 - m0), w1 = __expf(v1 - m1);
                den0 += w0; den1 += w1;
                s_idx[wid][lane] = s;
                s_w[wid][lane][0] = w0;
                s_w[wid][lane][1] = w1;
            }
            for (int j = 0; j < len; ++j) {
                int  si = s_idx[wid][j];
                float w = s_w[wid][j][hh_head];
                float2 v = __half22float2(h2[(size_t)si * 64 + lane]);
                acc.x = fmaf(w, v.x, acc.x);
                acc.y = fmaf(w, v.y, acc.y);
            }
        }
    }

    for (int o = 32; o; o >>= 1) {
        den0 += __shfl_xor(den0, o);
        den1 += __shfl_xor(den1, o);
    }
    float inv = 1.f / ((hh_head ? den1 : den0) + 1e-16f);
    float2 r = {acc.x * inv, acc.y * inv};

    if (CONCAT) {
        float2 b = *(const float2*)(bias + lane * 2);
        float2 o2 = {r.x + b.x, r.y + b.y};
        *(float2*)(out + (size_t)dnode * 128 + lane * 2) = o2;
    } else {
        float ox = __shfl_xor(r.x, 32);
        float oy = __shfl_xor(r.y, 32);
        if (lane < 32) {
            float2 b = *(const float2*)(bias + lane * 2);
            float2 o2 = {0.5f * (r.x + ox) + b.x, 0.5f * (r.y + oy) + b.y};
            *(float2*)(out + (size_t)dnode * 64 + lane * 2) = o2;
        }
    }
}

// ---------------- final pair dot ----------------

__global__ void pair_dot_kernel(const float* __restrict__ emb, const int* __restrict__ ui,
                                const int* __restrict__ ii, float* __restrict__ out, int B) {
    int w    = blockIdx.x * 4 + (threadIdx.x >> 6);
    int lane = threadIdx.x & 63;
    if (w >= B) return;
    float a = emb[(size_t)ui[w] * 64 + lane];
    float b = emb[(size_t)(NU_NODES + ii[w]) * 64 + lane];
    float p = a * b;
    for (int o = 32; o; o >>= 1) p += __shfl_xor(p, o);
    if (lane == 0) out[w] = p;
}

extern "C" void kernel_launch(void* const* d_in, const int* in_sizes, int n_in,
                              void* d_out, int out_size, void* d_ws, size_t ws_size,
                              hipStream_t stream) {
    const float* Gu       = (const float*)d_in[0];
    const float* Gi       = (const float*)d_in[1];
    const float* W0       = (const float*)d_in[2];
    const float* att_src0 = (const float*)d_in[3];
    const float* att_dst0 = (const float*)d_in[4];
    const float* b0       = (const float*)d_in[5];
    const float* W1       = (const float*)d_in[6];
    const float* att_src1 = (const float*)d_in[7];
    const float* att_dst1 = (const float*)d_in[8];
    const float* b1       = (const float*)d_in[9];
    const int* edge_index = (const int*)d_in[10];
    const int* user_idx   = (const int*)d_in[11];
    const int* item_idx   = (const int*)d_in[12];
    float* outp           = (float*)d_out;

    const int N = N_NODES, E = E_EDGES;
    char* wsp = (char*)d_ws;
    auto alloc = [&](size_t bytes) {
        void* p = wsp;
        wsp += (bytes + 255) & ~(size_t)255;
        return p;
    };
    float*  emb = (float*)alloc((size_t)N * 64 * 4);    // final embeddings
    __half* hh  = (__half*)alloc((size_t)N * 128 * 2);  // fp16 h (both layers)
    float*  x1  = (float*)alloc((size_t)N * 128 * 4);   // layer0 output (f32)
    float*  a_s = (float*)alloc((size_t)N * 2 * 4);
    float*  a_d = (float*)alloc((size_t)N * 2 * 4);
    int* row_ptr    = (int*)alloc((size_t)(N + 1) * 4);
    int* counts     = (int*)alloc((size_t)N * 4);
    int* fill       = (int*)alloc((size_t)N * 4);
    int* bsums      = (int*)alloc(256 * 4);
    int* src_sorted = (int*)alloc((size_t)E * 4);

    const int* esrc = edge_index;
    const int* edst = edge_index + E;

    // CSR by dst
    hipMemsetAsync(counts, 0, (size_t)N * 4, stream);
    hipMemsetAsync(fill, 0, (size_t)N * 4, stream);
    hist_kernel<<<E / 256, 256, 0, stream>>>(edst, counts, E);
    int nb = (N + 1023) / 1024;
    scan_blocks_kernel<<<nb, 1024, 0, stream>>>(counts, row_ptr, bsums, N);
    scan_sums_kernel<<<1, 256, 0, stream>>>(bsums, nb);
    add_offsets_kernel<<<(N + 255) / 256, 256, 0, stream>>>(row_ptr, bsums, N);
    scatter_kernel<<<E / 256, 256, 0, stream>>>(esrc, edst, row_ptr, fill, src_sorted, E);

    // layer 0 (A read directly from Gu/Gi; h fp16 + att dots fused)
    gemm_kernel<64><<<N / 128, 256, 0, stream>>>(Gu, Gi, NU_NODES, W0, att_src0, att_dst0,
                                                 hh, a_s, a_d);
    gat_agg_kernel<true><<<(N + 3) / 4, 256, 0, stream>>>(hh, row_ptr, src_sorted, a_s, a_d,
                                                          b0, x1);

    // layer 1
    gemm_kernel<128><<<N / 128, 256, 0, stream>>>(x1, x1, N, W1, att_src1, att_dst1,
                                                  hh, a_s, a_d);
    gat_agg_kernel<false><<<(N + 3) / 4, 256, 0, stream>>>(hh, row_ptr, src_sorted, a_s, a_d,
                                                           b1, emb);

    // final dot
    pair_dot_kernel<<<B_PAIRS / 4, 256, 0, stream>>>(emb, user_idx, item_idx, outp, B_PAIRS);
}

// Round 6
// 344.360 us; speedup vs baseline: 1.7862x; 1.0128x over previous
//
#include <hip/hip_runtime.h>
#include <hip/hip_fp16.h>
#include <math.h>

#define N_NODES   80000
#define NU_NODES  40000
#define E_EDGES   1280000
#define B_PAIRS   8192
#define NEG_SLOPE 0.2f
#define NBUCK     313   // ceil(N_NODES / 256)

// ---------------- row_ptr build (exact-dst histogram + scan) ----------------

__global__ void hist_kernel(const int* __restrict__ dst, int* __restrict__ counts, int E) {
    int e = blockIdx.x * 256 + threadIdx.x;
    if (e < E) atomicAdd(&counts[dst[e]], 1);
}

__global__ void scan_blocks_kernel(const int* __restrict__ counts, int* __restrict__ row_ptr,
                                   int* __restrict__ bsums, int n) {
    __shared__ int tmp[1024];
    int gid = blockIdx.x * 1024 + threadIdx.x;
    int v = (gid < n) ? counts[gid] : 0;
    tmp[threadIdx.x] = v;
    __syncthreads();
    for (int off = 1; off < 1024; off <<= 1) {
        int t = (threadIdx.x >= off) ? tmp[threadIdx.x - off] : 0;
        __syncthreads();
        tmp[threadIdx.x] += t;
        __syncthreads();
    }
    if (gid < n) row_ptr[gid + 1] = tmp[threadIdx.x];
    if (threadIdx.x == 1023) bsums[blockIdx.x] = tmp[1023];
}

__global__ void scan_sums_kernel(int* bsums, int nb) {
    __shared__ int tmp[256];
    int v = (threadIdx.x < nb) ? bsums[threadIdx.x] : 0;
    tmp[threadIdx.x] = v;
    __syncthreads();
    for (int off = 1; off < 256; off <<= 1) {
        int t = (threadIdx.x >= off) ? tmp[threadIdx.x - off] : 0;
        __syncthreads();
        tmp[threadIdx.x] += t;
        __syncthreads();
    }
    if (threadIdx.x < nb) bsums[threadIdx.x] = tmp[threadIdx.x] - v;  // exclusive
}

__global__ void add_offsets_kernel(int* row_ptr, const int* __restrict__ bsums, int n) {
    int gid = blockIdx.x * 256 + threadIdx.x;
    if (gid < n) row_ptr[gid + 1] += bsums[gid >> 10];
    if (gid == 0) row_ptr[0] = 0;
}

// ---------------- two-level binned CSR scatter (kills write amplification) ----------------
// K0: coarse bucket (dst>>8) histogram

__global__ __launch_bounds__(256) void bhist_kernel(const int* __restrict__ dst,
                                                    int* __restrict__ bucketCount, int E) {
    __shared__ int histL[NBUCK];
    for (int i = threadIdx.x; i < NBUCK; i += 256) histL[i] = 0;
    __syncthreads();
    int base = blockIdx.x * 16384;
    for (int r = 0; r < 64; ++r) {
        int e = base + r * 256 + threadIdx.x;
        if (e < E) atomicAdd(&histL[dst[e] >> 8], 1);
    }
    __syncthreads();
    for (int i = threadIdx.x; i < NBUCK; i += 256)
        if (histL[i]) atomicAdd(&bucketCount[i], histL[i]);
}

// K0b: single-block scan over NBUCK buckets -> bucket_ptr (and gfill running bases)

__global__ __launch_bounds__(512) void bscan_kernel(const int* __restrict__ bucketCount,
                                                    int* __restrict__ bucket_ptr,
                                                    int* __restrict__ gfill) {
    __shared__ int tmp[512];
    int t = threadIdx.x;
    int v = (t < NBUCK) ? bucketCount[t] : 0;
    tmp[t] = v;
    __syncthreads();
    for (int off = 1; off < 512; off <<= 1) {
        int x = (t >= off) ? tmp[t - off] : 0;
        __syncthreads();
        tmp[t] += x;
        __syncthreads();
    }
    int excl = tmp[t] - v;
    if (t < NBUCK) {
        bucket_ptr[t] = excl;
        gfill[t]      = excl;
        if (t == NBUCK - 1) bucket_ptr[NBUCK] = excl + v;
    }
}

// K1: binned scatter of packed (dst,src) into bucket-grouped runs (coalesced writes)

__global__ __launch_bounds__(256) void bscatter_kernel(const int* __restrict__ src,
                                                       const int* __restrict__ dst,
                                                       int* __restrict__ gfill,
                                                       unsigned long long* __restrict__ pk,
                                                       int E) {
    __shared__ int histL[NBUCK];
    __shared__ int baseL[NBUCK];
    __shared__ int rankL[NBUCK];
    for (int i = threadIdx.x; i < NBUCK; i += 256) { histL[i] = 0; rankL[i] = 0; }
    __syncthreads();
    int base = blockIdx.x * 16384;
    for (int r = 0; r < 64; ++r) {
        int e = base + r * 256 + threadIdx.x;
        if (e < E) atomicAdd(&histL[dst[e] >> 8], 1);
    }
    __syncthreads();
    for (int i = threadIdx.x; i < NBUCK; i += 256)
        baseL[i] = histL[i] ? atomicAdd(&gfill[i], histL[i]) : 0;
    __syncthreads();
    for (int r = 0; r < 64; ++r) {
        int e = base + r * 256 + threadIdx.x;
        if (e < E) {
            int d = dst[e];
            int b = d >> 8;
            int rk = atomicAdd(&rankL[b], 1);
            pk[baseL[b] + rk] = ((unsigned long long)(unsigned)d << 32) | (unsigned)src[e];
        }
    }
}

// K2: exact scatter within each bucket; one block per bucket, all writes for a
// node's list come from this block (one XCD, temporally close) -> no line thrash.

__global__ __launch_bounds__(256) void escatter_kernel(const unsigned long long* __restrict__ pk,
                                                       const int* __restrict__ bucket_ptr,
                                                       const int* __restrict__ row_ptr,
                                                       int* __restrict__ src_sorted) {
    __shared__ int fillL[256];
    __shared__ int rpL[256];
    int b = blockIdx.x;
    int node0 = b << 8;
    int nn = N_NODES - node0; if (nn > 256) nn = 256;
    fillL[threadIdx.x] = 0;
    rpL[threadIdx.x]   = (threadIdx.x < nn) ? row_ptr[node0 + threadIdx.x] : 0;
    __syncthreads();
    int s = bucket_ptr[b], e = bucket_ptr[b + 1];
    for (int k = s + threadIdx.x; k < e; k += 256) {
        unsigned long long p = pk[k];
        int lo = (int)(p >> 32) & 255;
        int pos = atomicAdd(&fillL[lo], 1);
        src_sorted[rpL[lo] + pos] = (int)(unsigned)p;
    }
}

// ---------------- GEMM + fused attention-dot epilogue ----------------
// [M,K] @ [K,128] -> h (fp16) and a_s/a_d (f32 dots vs att vectors).
// 128x128 block tile, 256 threads, 8x8 micro-tile, K chunked by 32.
// Register-pressure discipline (R4 spilled): k-loop unroll 2 only, att
// vectors staged in LDS (read AFTER the last barrier, can't be hoisted),
// A staging pointers precomputed once.

#define FMA4(dst, av, bv)                 \
    dst.x = fmaf(av, bv.x, dst.x);        \
    dst.y = fmaf(av, bv.y, dst.y);        \
    dst.z = fmaf(av, bv.z, dst.z);        \
    dst.w = fmaf(av, bv.w, dst.w);

#define DOT4(a, b) (a.x * b.x + a.y * b.y + a.z * b.z + a.w * b.w)

struct alignas(8) H4 { __half2 a, b; };

template <int K>
__global__ __launch_bounds__(256, 4) void gemm_kernel(const float* __restrict__ A0,
                                                      const float* __restrict__ A1, int split,
                                                      const float* __restrict__ W,
                                                      const float* __restrict__ attS,
                                                      const float* __restrict__ attD,
                                                      __half* __restrict__ hh,
                                                      float* __restrict__ a_s,
                                                      float* __restrict__ a_d) {
    __shared__ float As[32][128];  // As[k][row ^ ((k&7)<<2)] = A[row0+row][k0+k]
    __shared__ float Bs[32][128];  // Bs[k][col]              = W[k0+k][col]
    __shared__ float attL[256];    // [0:128)=attS, [128:256)=attD
    const int tid  = threadIdx.x;
    const int row0 = blockIdx.x * 128;
    const int tc   = tid & 15;  // col group: cols tc*4+{0..3} and 64+tc*4+{0..3}
    const int tr   = tid >> 4;  // row group: rows tr*4+{0..3} and 64+tr*4+{0..3}

    attL[tid] = (tid < 128) ? attS[tid] : attD[tid - 128];

    // per-thread A staging pointers (4 fixed rows per thread across all k-chunks)
    const float* aptr[4];
#pragma unroll
    for (int p = 0; p < 4; ++p) {
        int idx  = tid + p * 256;
        int r    = idx >> 3;
        int grow = row0 + r;
        aptr[p] = (grow < split) ? (A0 + (size_t)grow * K) : (A1 + (size_t)(grow - split) * K);
    }

    float4 acc[2][2][4];
#pragma unroll
    for (int a = 0; a < 2; ++a)
#pragma unroll
        for (int b = 0; b < 2; ++b)
#pragma unroll
            for (int i = 0; i < 4; ++i) acc[a][b][i] = make_float4(0.f, 0.f, 0.f, 0.f);

#pragma unroll 1
    for (int k0 = 0; k0 < K; k0 += 32) {
#pragma unroll
        for (int p = 0; p < 4; ++p) {
            int idx = tid + p * 256;
            int r = idx >> 5, c4 = idx & 31;
            *(float4*)&Bs[r][c4 * 4] = *(const float4*)&W[(size_t)(k0 + r) * 128 + c4 * 4];
        }
#pragma unroll
        for (int p = 0; p < 4; ++p) {
            int idx = tid + p * 256;
            int r = idx >> 3, kq = idx & 7;
            float4 v = *(const float4*)&aptr[p][k0 + kq * 4];
            int kk = kq * 4;
            As[kk + 0][r ^ (((kk + 0) & 7) << 2)] = v.x;
            As[kk + 1][r ^ (((kk + 1) & 7) << 2)] = v.y;
            As[kk + 2][r ^ (((kk + 2) & 7) << 2)] = v.z;
            As[kk + 3][r ^ (((kk + 3) & 7) << 2)] = v.w;
        }
        __syncthreads();
#pragma unroll 2
        for (int k = 0; k < 32; ++k) {
            int sw = (k & 7) << 2;
            float4 a0 = *(const float4*)&As[k][(tr * 4) ^ sw];
            float4 a1 = *(const float4*)&As[k][(64 + tr * 4) ^ sw];
            float4 b0 = *(const float4*)&Bs[k][tc * 4];
            float4 b1 = *(const float4*)&Bs[k][64 + tc * 4];
#pragma unroll
            for (int i = 0; i < 4; ++i) {
                float ar0 = ((const float*)&a0)[i];
                float ar1 = ((const float*)&a1)[i];
                FMA4(acc[0][0][i], ar0, b0);
                FMA4(acc[0][1][i], ar0, b1);
                FMA4(acc[1][0][i], ar1, b0);
                FMA4(acc[1][1][i], ar1, b1);
            }
        }
        __syncthreads();
    }

    // epilogue: att vectors from LDS (post-barrier => not hoisted into the loop)
    const float4 vs0 = *(const float4*)&attL[tc * 4];
    const float4 vs1 = *(const float4*)&attL[64 + tc * 4];
    const float4 vd0 = *(const float4*)&attL[128 + tc * 4];
    const float4 vd1 = *(const float4*)&attL[192 + tc * 4];
#pragma unroll
    for (int rh = 0; rh < 2; ++rh)
#pragma unroll
        for (int i = 0; i < 4; ++i) {
            int row = row0 + rh * 64 + tr * 4 + i;
            float4 a0 = acc[rh][0][i];
            float4 a1 = acc[rh][1][i];
            H4 h0, h1;
            h0.a = __float22half2_rn(make_float2(a0.x, a0.y));
            h0.b = __float22half2_rn(make_float2(a0.z, a0.w));
            h1.a = __float22half2_rn(make_float2(a1.x, a1.y));
            h1.b = __float22half2_rn(make_float2(a1.z, a1.w));
            *(H4*)(hh + (size_t)row * 128 + tc * 4)      = h0;
            *(H4*)(hh + (size_t)row * 128 + 64 + tc * 4) = h1;
            float s0 = DOT4(a0, vs0), s1 = DOT4(a1, vs1);
            float d0 = DOT4(a0, vd0), d1 = DOT4(a1, vd1);
#pragma unroll
            for (int o = 1; o < 16; o <<= 1) {
                s0 += __shfl_xor(s0, o);
                s1 += __shfl_xor(s1, o);
                d0 += __shfl_xor(d0, o);
                d1 += __shfl_xor(d1, o);
            }
            if (tc == 0) {
                *(float2*)&a_s[row * 2] = make_float2(s0, s1);
                *(float2*)&a_d[row * 2] = make_float2(d0, d1);
            }
        }
}

// ---------------- GAT aggregation: one WAVE per dst node, both heads ----------------
// lane covers channels (2*lane, 2*lane+1); head = lane>>5. h is fp16 (256B/row).

template <bool CONCAT>
__global__ __launch_bounds__(256) void gat_agg_kernel(const __half* __restrict__ hh,
        const int* __restrict__ row_ptr, const int* __restrict__ src_sorted,
        const float* __restrict__ a_s, const float* __restrict__ a_d,
        const float* __restrict__ bias, float* __restrict__ out) {
    __shared__ int   s_idx[4][64];
    __shared__ float s_w[4][64][2];
    int wid   = threadIdx.x >> 6;
    int lane  = threadIdx.x & 63;
    int dnode = blockIdx.x * 4 + wid;
    if (dnode >= N_NODES) return;
    int start = row_ptr[dnode], end = row_ptr[dnode + 1];
    int deg = end - start;
    float2 ad = *(const float2*)(a_d + dnode * 2);
    int hh_head = lane >> 5;
    float2 acc = {0.f, 0.f};
    float den0 = 0.f, den1 = 0.f;
    const __half2* h2 = (const __half2*)hh;

    if (deg <= 64) {  // fast path
        float v0 = -INFINITY, v1 = -INFINITY;
        int s = 0;
        if (lane < deg) {
            s = src_sorted[start + lane];
            float2 as = *(const float2*)(a_s + s * 2);
            v0 = as.x + ad.x; v0 = v0 > 0.f ? v0 : NEG_SLOPE * v0;
            v1 = as.y + ad.y; v1 = v1 > 0.f ? v1 : NEG_SLOPE * v1;
        }
        float m0 = v0, m1 = v1;
        for (int o = 32; o; o >>= 1) {
            m0 = fmaxf(m0, __shfl_xor(m0, o));
            m1 = fmaxf(m1, __shfl_xor(m1, o));
        }
        if (lane < deg) {
            float w0 = __expf(v0 - m0), w1 = __expf(v1 - m1);
            den0 = w0; den1 = w1;
            s_idx[wid][lane] = s;
            s_w[wid][lane][0] = w0;
            s_w[wid][lane][1] = w1;
        }
        for (int j = 0; j < deg; ++j) {
            int  si = s_idx[wid][j];
            float w = s_w[wid][j][hh_head];
            float2 v = __half22float2(h2[(size_t)si * 64 + lane]);
            acc.x = fmaf(w, v.x, acc.x);
            acc.y = fmaf(w, v.y, acc.y);
        }
    } else {  // general path (rare for Poisson(16))
        float m0 = -INFINITY, m1 = -INFINITY;
        for (int k = start + lane; k < end; k += 64) {
            int s = src_sorted[k];
            float2 as = *(const float2*)(a_s + s * 2);
            float v0 = as.x + ad.x; v0 = v0 > 0.f ? v0 : NEG_SLOPE * v0;
            float v1 = as.y + ad.y; v1 = v1 > 0.f ? v1 : NEG_SLOPE * v1;
            m0 = fmaxf(m0, v0); m1 = fmaxf(m1, v1);
        }
        for (int o = 32; o; o >>= 1) {
            m0 = fmaxf(m0, __shfl_xor(m0, o));
            m1 = fmaxf(m1, __shfl_xor(m1, o));
        }
        for (int c0 = start; c0 < end; c0 += 64) {
            int len = min(64, end - c0);
            if (lane < len) {
                int s = src_sorted[c0 + lane];
                float2 as = *(const float2*)(a_s + s * 2);
                float v0 = as.x + ad.x; v0 = v0 > 0.f ? v0 : NEG_SLOPE * v0;
                float v1 = as.y + ad.y; v1 = v1 > 0.f ? v1 : NEG_SLOPE * v1;
                float w0 = __expf(v0 - m0), w1 = __expf(v1 - m1);
                den0 += w0; den1 += w1;
                s_idx[wid][lane] = s;
                s_w[wid][lane][0] = w0;
                s_w[wid][lane][1] = w1;
            }
            for (int j = 0; j < len; ++j) {
                int  si = s_idx[wid][j];
                float w = s_w[wid][j][hh_head];
                float2 v = __half22float2(h2[(size_t)si * 64 + lane]);
                acc.x = fmaf(w, v.x, acc.x);
                acc.y = fmaf(w, v.y, acc.y);
            }
        }
    }

    for (int o = 32; o; o >>= 1) {
        den0 += __shfl_xor(den0, o);
        den1 += __shfl_xor(den1, o);
    }
    float inv = 1.f / ((hh_head ? den1 : den0) + 1e-16f);
    float2 r = {acc.x * inv, acc.y * inv};

    if (CONCAT) {
        float2 b = *(const float2*)(bias + lane * 2);
        float2 o2 = {r.x + b.x, r.y + b.y};
        *(float2*)(out + (size_t)dnode * 128 + lane * 2) = o2;
    } else {
        float ox = __shfl_xor(r.x, 32);
        float oy = __shfl_xor(r.y, 32);
        if (lane < 32) {
            float2 b = *(const float2*)(bias + lane * 2);
            float2 o2 = {0.5f * (r.x + ox) + b.x, 0.5f * (r.y + oy) + b.y};
            *(float2*)(out + (size_t)dnode * 64 + lane * 2) = o2;
        }
    }
}

// ---------------- final pair dot ----------------

__global__ void pair_dot_kernel(const float* __restrict__ emb, const int* __restrict__ ui,
                                const int* __restrict__ ii, float* __restrict__ out, int B) {
    int w    = blockIdx.x * 4 + (threadIdx.x >> 6);
    int lane = threadIdx.x & 63;
    if (w >= B) return;
    float a = emb[(size_t)ui[w] * 64 + lane];
    float b = emb[(size_t)(NU_NODES + ii[w]) * 64 + lane];
    float p = a * b;
    for (int o = 32; o; o >>= 1) p += __shfl_xor(p, o);
    if (lane == 0) out[w] = p;
}

extern "C" void kernel_launch(void* const* d_in, const int* in_sizes, int n_in,
                              void* d_out, int out_size, void* d_ws, size_t ws_size,
                              hipStream_t stream) {
    const float* Gu       = (const float*)d_in[0];
    const float* Gi       = (const float*)d_in[1];
    const float* W0       = (const float*)d_in[2];
    const float* att_src0 = (const float*)d_in[3];
    const float* att_dst0 = (const float*)d_in[4];
    const float* b0       = (const float*)d_in[5];
    const float* W1       = (const float*)d_in[6];
    const float* att_src1 = (const float*)d_in[7];
    const float* att_dst1 = (const float*)d_in[8];
    const float* b1       = (const float*)d_in[9];
    const int* edge_index = (const int*)d_in[10];
    const int* user_idx   = (const int*)d_in[11];
    const int* item_idx   = (const int*)d_in[12];
    float* outp           = (float*)d_out;

    const int N = N_NODES, E = E_EDGES;
    char* wsp = (char*)d_ws;
    auto alloc = [&](size_t bytes) {
        void* p = wsp;
        wsp += (bytes + 255) & ~(size_t)255;
        return p;
    };
    float*  emb = (float*)alloc((size_t)N * 64 * 4);    // final embeddings
    __half* hh  = (__half*)alloc((size_t)N * 128 * 2);  // fp16 h (both layers)
    float*  x1  = (float*)alloc((size_t)N * 128 * 4);   // layer0 output (f32)
    float*  a_s = (float*)alloc((size_t)N * 2 * 4);
    float*  a_d = (float*)alloc((size_t)N * 2 * 4);
    int* row_ptr    = (int*)alloc((size_t)(N + 1) * 4);
    int* counts     = (int*)alloc((size_t)N * 4);
    int* bsums      = (int*)alloc(256 * 4);
    int* src_sorted = (int*)alloc((size_t)E * 4);
    int* bucketCount = (int*)alloc((NBUCK + 1) * 4);
    int* bucket_ptr  = (int*)alloc((NBUCK + 1) * 4);
    int* gfill       = (int*)alloc((NBUCK + 1) * 4);
    // pk only lives during CSR build; x1 only after -> overlay (10.3MB << 41MB)
    unsigned long long* pk = (unsigned long long*)x1;

    const int* esrc = edge_index;
    const int* edst = edge_index + E;

    // row_ptr (exact-dst histogram + hierarchical scan)
    hipMemsetAsync(counts, 0, (size_t)N * 4, stream);
    hipMemsetAsync(bucketCount, 0, (NBUCK + 1) * 4, stream);
    hist_kernel<<<E / 256, 256, 0, stream>>>(edst, counts, E);
    int nb = (N + 1023) / 1024;
    scan_blocks_kernel<<<nb, 1024, 0, stream>>>(counts, row_ptr, bsums, N);
    scan_sums_kernel<<<1, 256, 0, stream>>>(bsums, nb);
    add_offsets_kernel<<<(N + 255) / 256, 256, 0, stream>>>(row_ptr, bsums, N);

    // two-level binned scatter -> src_sorted (CSR adjacency by dst)
    int nbk = (E + 16383) / 16384;
    bhist_kernel<<<nbk, 256, 0, stream>>>(edst, bucketCount, E);
    bscan_kernel<<<1, 512, 0, stream>>>(bucketCount, bucket_ptr, gfill);
    bscatter_kernel<<<nbk, 256, 0, stream>>>(esrc, edst, gfill, pk, E);
    escatter_kernel<<<NBUCK, 256, 0, stream>>>(pk, bucket_ptr, row_ptr, src_sorted);

    // layer 0 (A read directly from Gu/Gi; h fp16 + att dots fused)
    gemm_kernel<64><<<N / 128, 256, 0, stream>>>(Gu, Gi, NU_NODES, W0, att_src0, att_dst0,
                                                 hh, a_s, a_d);
    gat_agg_kernel<true><<<(N + 3) / 4, 256, 0, stream>>>(hh, row_ptr, src_sorted, a_s, a_d,
                                                          b0, x1);

    // layer 1
    gemm_kernel<128><<<N / 128, 256, 0, stream>>>(x1, x1, N, W1, att_src1, att_dst1,
                                                  hh, a_s, a_d);
    gat_agg_kernel<false><<<(N + 3) / 4, 256, 0, stream>>>(hh, row_ptr, src_sorted, a_s, a_d,
                                                           b1, emb);

    // final dot
    pair_dot_kernel<<<B_PAIRS / 4, 256, 0, stream>>>(emb, user_idx, item_idx, outp, B_PAIRS);
}

// Round 7
// 297.520 us; speedup vs baseline: 2.0674x; 1.1574x over previous
//
#include <hip/hip_runtime.h>
#include <hip/hip_fp16.h>
#include <math.h>

#define N_NODES   80000
#define NU_NODES  40000
#define E_EDGES   1280000
#define B_PAIRS   8192
#define NEG_SLOPE 0.2f
#define NBUCK     313   // ceil(N_NODES / 256)
#define SCHUNK    2048  // edges per bscatter block (625 blocks -> real occupancy)

// ---------------- row_ptr build (exact-dst histogram + scan) ----------------

__global__ void hist_kernel(const int* __restrict__ dst, int* __restrict__ counts, int E) {
    int e = blockIdx.x * 256 + threadIdx.x;
    if (e < E) atomicAdd(&counts[dst[e]], 1);
}

__global__ void scan_blocks_kernel(const int* __restrict__ counts, int* __restrict__ row_ptr,
                                   int* __restrict__ bsums, int n) {
    __shared__ int tmp[1024];
    int gid = blockIdx.x * 1024 + threadIdx.x;
    int v = (gid < n) ? counts[gid] : 0;
    tmp[threadIdx.x] = v;
    __syncthreads();
    for (int off = 1; off < 1024; off <<= 1) {
        int t = (threadIdx.x >= off) ? tmp[threadIdx.x - off] : 0;
        __syncthreads();
        tmp[threadIdx.x] += t;
        __syncthreads();
    }
    if (gid < n) row_ptr[gid + 1] = tmp[threadIdx.x];
    if (threadIdx.x == 1023) bsums[blockIdx.x] = tmp[1023];
}

__global__ void scan_sums_kernel(int* bsums, int nb) {
    __shared__ int tmp[256];
    int v = (threadIdx.x < nb) ? bsums[threadIdx.x] : 0;
    tmp[threadIdx.x] = v;
    __syncthreads();
    for (int off = 1; off < 256; off <<= 1) {
        int t = (threadIdx.x >= off) ? tmp[threadIdx.x - off] : 0;
        __syncthreads();
        tmp[threadIdx.x] += t;
        __syncthreads();
    }
    if (threadIdx.x < nb) bsums[threadIdx.x] = tmp[threadIdx.x] - v;  // exclusive
}

__global__ void add_offsets_kernel(int* row_ptr, const int* __restrict__ bsums, int n) {
    int gid = blockIdx.x * 256 + threadIdx.x;
    if (gid < n) row_ptr[gid + 1] += bsums[gid >> 10];
    if (gid == 0) row_ptr[0] = 0;
}

// bucket_ptr[b] = row_ptr[b*256] (buckets are 256 consecutive dst nodes; CSR
// offsets monotone) -> no separate bucket histogram/scan passes needed.
__global__ void derive_buckets_kernel(const int* __restrict__ row_ptr,
                                      int* __restrict__ bucket_ptr, int* __restrict__ gfill) {
    int t = blockIdx.x * 256 + threadIdx.x;
    if (t <= NBUCK) {
        int idx = t << 8;
        if (idx > N_NODES) idx = N_NODES;
        int v = row_ptr[idx];
        bucket_ptr[t] = v;
        if (t < NBUCK) gfill[t] = v;
    }
}

// K1: binned scatter of packed (dst,src) into bucket-grouped runs.
// 512 thr x 625 blocks: enough waves to hide the load->LDS-atomic->store chain.

__global__ __launch_bounds__(512) void bscatter_kernel(const int* __restrict__ src,
                                                       const int* __restrict__ dst,
                                                       int* __restrict__ gfill,
                                                       unsigned long long* __restrict__ pk,
                                                       int E) {
    __shared__ int histL[NBUCK];
    __shared__ int baseL[NBUCK];
    __shared__ int rankL[NBUCK];
    for (int i = threadIdx.x; i < NBUCK; i += 512) { histL[i] = 0; rankL[i] = 0; }
    __syncthreads();
    int base = blockIdx.x * SCHUNK;
#pragma unroll
    for (int r = 0; r < SCHUNK / 512; ++r) {
        int e = base + r * 512 + threadIdx.x;
        if (e < E) atomicAdd(&histL[dst[e] >> 8], 1);
    }
    __syncthreads();
    for (int i = threadIdx.x; i < NBUCK; i += 512)
        baseL[i] = histL[i] ? atomicAdd(&gfill[i], histL[i]) : 0;
    __syncthreads();
#pragma unroll
    for (int r = 0; r < SCHUNK / 512; ++r) {
        int e = base + r * 512 + threadIdx.x;
        if (e < E) {
            int d = dst[e];
            int b = d >> 8;
            int rk = atomicAdd(&rankL[b], 1);
            pk[baseL[b] + rk] = ((unsigned long long)(unsigned)d << 32) | (unsigned)src[e];
        }
    }
}

// K2: exact scatter within each bucket; one block per bucket, all writes for a
// node's list come from one block (one XCD, temporally close) -> no line thrash.

__global__ __launch_bounds__(256) void escatter_kernel(const unsigned long long* __restrict__ pk,
                                                       const int* __restrict__ bucket_ptr,
                                                       const int* __restrict__ row_ptr,
                                                       int* __restrict__ src_sorted) {
    __shared__ int fillL[256];
    __shared__ int rpL[256];
    int b = blockIdx.x;
    int node0 = b << 8;
    int nn = N_NODES - node0; if (nn > 256) nn = 256;
    fillL[threadIdx.x] = 0;
    rpL[threadIdx.x]   = (threadIdx.x < nn) ? row_ptr[node0 + threadIdx.x] : 0;
    __syncthreads();
    int s = bucket_ptr[b], e = bucket_ptr[b + 1];
    for (int k = s + threadIdx.x; k < e; k += 256) {
        unsigned long long p = pk[k];
        int lo = (int)(p >> 32) & 255;
        int pos = atomicAdd(&fillL[lo], 1);
        src_sorted[rpL[lo] + pos] = (int)(unsigned)p;
    }
}

// ---------------- GEMM + fused attention-dot epilogue ----------------
// [M,K] @ [K,128] -> h (fp16) and a_s/a_d (f32 dots vs att vectors).
// 128x128 block tile, 256 threads, 8x8 micro-tile, K chunked by 32.
// Register-pressure discipline (R4 spilled): k-loop unroll 2 only, att
// vectors staged in LDS (read AFTER the last barrier, can't be hoisted),
// A staging pointers precomputed once.

#define FMA4(dst, av, bv)                 \
    dst.x = fmaf(av, bv.x, dst.x);        \
    dst.y = fmaf(av, bv.y, dst.y);        \
    dst.z = fmaf(av, bv.z, dst.z);        \
    dst.w = fmaf(av, bv.w, dst.w);

#define DOT4(a, b) (a.x * b.x + a.y * b.y + a.z * b.z + a.w * b.w)

struct alignas(8) H4 { __half2 a, b; };

template <int K>
__global__ __launch_bounds__(256, 4) void gemm_kernel(const float* __restrict__ A0,
                                                      const float* __restrict__ A1, int split,
                                                      const float* __restrict__ W,
                                                      const float* __restrict__ attS,
                                                      const float* __restrict__ attD,
                                                      __half* __restrict__ hh,
                                                      float* __restrict__ a_s,
                                                      float* __restrict__ a_d) {
    __shared__ float As[32][128];  // As[k][row ^ ((k&7)<<2)] = A[row0+row][k0+k]
    __shared__ float Bs[32][128];  // Bs[k][col]              = W[k0+k][col]
    __shared__ float attL[256];    // [0:128)=attS, [128:256)=attD
    const int tid  = threadIdx.x;
    const int row0 = blockIdx.x * 128;
    const int tc   = tid & 15;  // col group: cols tc*4+{0..3} and 64+tc*4+{0..3}
    const int tr   = tid >> 4;  // row group: rows tr*4+{0..3} and 64+tr*4+{0..3}

    attL[tid] = (tid < 128) ? attS[tid] : attD[tid - 128];

    // per-thread A staging pointers (4 fixed rows per thread across all k-chunks)
    const float* aptr[4];
#pragma unroll
    for (int p = 0; p < 4; ++p) {
        int idx  = tid + p * 256;
        int r    = idx >> 3;
        int grow = row0 + r;
        aptr[p] = (grow < split) ? (A0 + (size_t)grow * K) : (A1 + (size_t)(grow - split) * K);
    }

    float4 acc[2][2][4];
#pragma unroll
    for (int a = 0; a < 2; ++a)
#pragma unroll
        for (int b = 0; b < 2; ++b)
#pragma unroll
            for (int i = 0; i < 4; ++i) acc[a][b][i] = make_float4(0.f, 0.f, 0.f, 0.f);

#pragma unroll 1
    for (int k0 = 0; k0 < K; k0 += 32) {
#pragma unroll
        for (int p = 0; p < 4; ++p) {
            int idx = tid + p * 256;
            int r = idx >> 5, c4 = idx & 31;
            *(float4*)&Bs[r][c4 * 4] = *(const float4*)&W[(size_t)(k0 + r) * 128 + c4 * 4];
        }
#pragma unroll
        for (int p = 0; p < 4; ++p) {
            int idx = tid + p * 256;
            int r = idx >> 3, kq = idx & 7;
            float4 v = *(const float4*)&aptr[p][k0 + kq * 4];
            int kk = kq * 4;
            As[kk + 0][r ^ (((kk + 0) & 7) << 2)] = v.x;
            As[kk + 1][r ^ (((kk + 1) & 7) << 2)] = v.y;
            As[kk + 2][r ^ (((kk + 2) & 7) << 2)] = v.z;
            As[kk + 3][r ^ (((kk + 3) & 7) << 2)] = v.w;
        }
        __syncthreads();
#pragma unroll 2
        for (int k = 0; k < 32; ++k) {
            int sw = (k & 7) << 2;
            float4 a0 = *(const float4*)&As[k][(tr * 4) ^ sw];
            float4 a1 = *(const float4*)&As[k][(64 + tr * 4) ^ sw];
            float4 b0 = *(const float4*)&Bs[k][tc * 4];
            float4 b1 = *(const float4*)&Bs[k][64 + tc * 4];
#pragma unroll
            for (int i = 0; i < 4; ++i) {
                float ar0 = ((const float*)&a0)[i];
                float ar1 = ((const float*)&a1)[i];
                FMA4(acc[0][0][i], ar0, b0);
                FMA4(acc[0][1][i], ar0, b1);
                FMA4(acc[1][0][i], ar1, b0);
                FMA4(acc[1][1][i], ar1, b1);
            }
        }
        __syncthreads();
    }

    // epilogue: att vectors from LDS (post-barrier => not hoisted into the loop)
    const float4 vs0 = *(const float4*)&attL[tc * 4];
    const float4 vs1 = *(const float4*)&attL[64 + tc * 4];
    const float4 vd0 = *(const float4*)&attL[128 + tc * 4];
    const float4 vd1 = *(const float4*)&attL[192 + tc * 4];
#pragma unroll
    for (int rh = 0; rh < 2; ++rh)
#pragma unroll
        for (int i = 0; i < 4; ++i) {
            int row = row0 + rh * 64 + tr * 4 + i;
            float4 a0 = acc[rh][0][i];
            float4 a1 = acc[rh][1][i];
            H4 h0, h1;
            h0.a = __float22half2_rn(make_float2(a0.x, a0.y));
            h0.b = __float22half2_rn(make_float2(a0.z, a0.w));
            h1.a = __float22half2_rn(make_float2(a1.x, a1.y));
            h1.b = __float22half2_rn(make_float2(a1.z, a1.w));
            *(H4*)(hh + (size_t)row * 128 + tc * 4)      = h0;
            *(H4*)(hh + (size_t)row * 128 + 64 + tc * 4) = h1;
            float s0 = DOT4(a0, vs0), s1 = DOT4(a1, vs1);
            float d0 = DOT4(a0, vd0), d1 = DOT4(a1, vd1);
#pragma unroll
            for (int o = 1; o < 16; o <<= 1) {
                s0 += __shfl_xor(s0, o);
                s1 += __shfl_xor(s1, o);
                d0 += __shfl_xor(d0, o);
                d1 += __shfl_xor(d1, o);
            }
            if (tc == 0) {
                *(float2*)&a_s[row * 2] = make_float2(s0, s1);
                *(float2*)&a_d[row * 2] = make_float2(d0, d1);
            }
        }
}

// ---------------- GAT aggregation: one WAVE per dst node, both heads ----------------
// lane covers channels (2*lane, 2*lane+1); head = lane>>5. h is fp16 (256B/row).
// j-loop unrolled x4 with batched loads -> 4 outstanding gathers per wave.

template <bool CONCAT>
__global__ __launch_bounds__(256) void gat_agg_kernel(const __half* __restrict__ hh,
        const int* __restrict__ row_ptr, const int* __restrict__ src_sorted,
        const float* __restrict__ a_s, const float* __restrict__ a_d,
        const float* __restrict__ bias, float* __restrict__ out) {
    __shared__ int   s_idx[4][64];
    __shared__ float s_w[4][64][2];
    int wid   = threadIdx.x >> 6;
    int lane  = threadIdx.x & 63;
    int dnode = blockIdx.x * 4 + wid;
    if (dnode >= N_NODES) return;
    int start = row_ptr[dnode], end = row_ptr[dnode + 1];
    int deg = end - start;
    float2 ad = *(const float2*)(a_d + dnode * 2);
    int hh_head = lane >> 5;
    float2 acc = {0.f, 0.f};
    float den0 = 0.f, den1 = 0.f;
    const __half2* h2 = (const __half2*)hh;

    if (deg <= 64) {  // fast path
        float v0 = -INFINITY, v1 = -INFINITY;
        int s = 0;
        if (lane < deg) {
            s = src_sorted[start + lane];
            float2 as = *(const float2*)(a_s + s * 2);
            v0 = as.x + ad.x; v0 = v0 > 0.f ? v0 : NEG_SLOPE * v0;
            v1 = as.y + ad.y; v1 = v1 > 0.f ? v1 : NEG_SLOPE * v1;
        }
        float m0 = v0, m1 = v1;
        for (int o = 32; o; o >>= 1) {
            m0 = fmaxf(m0, __shfl_xor(m0, o));
            m1 = fmaxf(m1, __shfl_xor(m1, o));
        }
        if (lane < deg) {
            float w0 = __expf(v0 - m0), w1 = __expf(v1 - m1);
            den0 = w0; den1 = w1;
            s_idx[wid][lane] = s;
            s_w[wid][lane][0] = w0;
            s_w[wid][lane][1] = w1;
        }
        int j = 0;
#pragma unroll 1
        for (; j + 4 <= deg; j += 4) {
            int   si0 = s_idx[wid][j + 0], si1 = s_idx[wid][j + 1];
            int   si2 = s_idx[wid][j + 2], si3 = s_idx[wid][j + 3];
            float w0 = s_w[wid][j + 0][hh_head], w1 = s_w[wid][j + 1][hh_head];
            float w2 = s_w[wid][j + 2][hh_head], w3 = s_w[wid][j + 3][hh_head];
            float2 q0 = __half22float2(h2[(size_t)si0 * 64 + lane]);
            float2 q1 = __half22float2(h2[(size_t)si1 * 64 + lane]);
            float2 q2 = __half22float2(h2[(size_t)si2 * 64 + lane]);
            float2 q3 = __half22float2(h2[(size_t)si3 * 64 + lane]);
            acc.x = fmaf(w0, q0.x, acc.x); acc.y = fmaf(w0, q0.y, acc.y);
            acc.x = fmaf(w1, q1.x, acc.x); acc.y = fmaf(w1, q1.y, acc.y);
            acc.x = fmaf(w2, q2.x, acc.x); acc.y = fmaf(w2, q2.y, acc.y);
            acc.x = fmaf(w3, q3.x, acc.x); acc.y = fmaf(w3, q3.y, acc.y);
        }
        for (; j < deg; ++j) {
            int  si = s_idx[wid][j];
            float w = s_w[wid][j][hh_head];
            float2 v = __half22float2(h2[(size_t)si * 64 + lane]);
            acc.x = fmaf(w, v.x, acc.x);
            acc.y = fmaf(w, v.y, acc.y);
        }
    } else {  // general path (rare for Poisson(16))
        float m0 = -INFINITY, m1 = -INFINITY;
        for (int k = start + lane; k < end; k += 64) {
            int s = src_sorted[k];
            float2 as = *(const float2*)(a_s + s * 2);
            float v0 = as.x + ad.x; v0 = v0 > 0.f ? v0 : NEG_SLOPE * v0;
            float v1 = as.y + ad.y; v1 = v1 > 0.f ? v1 : NEG_SLOPE * v1;
            m0 = fmaxf(m0, v0); m1 = fmaxf(m1, v1);
        }
        for (int o = 32; o; o >>= 1) {
            m0 = fmaxf(m0, __shfl_xor(m0, o));
            m1 = fmaxf(m1, __shfl_xor(m1, o));
        }
        for (int c0 = start; c0 < end; c0 += 64) {
            int len = min(64, end - c0);
            if (lane < len) {
                int s = src_sorted[c0 + lane];
                float2 as = *(const float2*)(a_s + s * 2);
                float v0 = as.x + ad.x; v0 = v0 > 0.f ? v0 : NEG_SLOPE * v0;
                float v1 = as.y + ad.y; v1 = v1 > 0.f ? v1 : NEG_SLOPE * v1;
                float w0 = __expf(v0 - m0), w1 = __expf(v1 - m1);
                den0 += w0; den1 += w1;
                s_idx[wid][lane] = s;
                s_w[wid][lane][0] = w0;
                s_w[wid][lane][1] = w1;
            }
            for (int j = 0; j < len; ++j) {
                int  si = s_idx[wid][j];
                float w = s_w[wid][j][hh_head];
                float2 v = __half22float2(h2[(size_t)si * 64 + lane]);
                acc.x = fmaf(w, v.x, acc.x);
                acc.y = fmaf(w, v.y, acc.y);
            }
        }
    }

    for (int o = 32; o; o >>= 1) {
        den0 += __shfl_xor(den0, o);
        den1 += __shfl_xor(den1, o);
    }
    float inv = 1.f / ((hh_head ? den1 : den0) + 1e-16f);
    float2 r = {acc.x * inv, acc.y * inv};

    if (CONCAT) {
        float2 b = *(const float2*)(bias + lane * 2);
        float2 o2 = {r.x + b.x, r.y + b.y};
        *(float2*)(out + (size_t)dnode * 128 + lane * 2) = o2;
    } else {
        float ox = __shfl_xor(r.x, 32);
        float oy = __shfl_xor(r.y, 32);
        if (lane < 32) {
            float2 b = *(const float2*)(bias + lane * 2);
            float2 o2 = {0.5f * (r.x + ox) + b.x, 0.5f * (r.y + oy) + b.y};
            *(float2*)(out + (size_t)dnode * 64 + lane * 2) = o2;
        }
    }
}

// ---------------- final pair dot ----------------

__global__ void pair_dot_kernel(const float* __restrict__ emb, const int* __restrict__ ui,
                                const int* __restrict__ ii, float* __restrict__ out, int B) {
    int w    = blockIdx.x * 4 + (threadIdx.x >> 6);
    int lane = threadIdx.x & 63;
    if (w >= B) return;
    float a = emb[(size_t)ui[w] * 64 + lane];
    float b = emb[(size_t)(NU_NODES + ii[w]) * 64 + lane];
    float p = a * b;
    for (int o = 32; o; o >>= 1) p += __shfl_xor(p, o);
    if (lane == 0) out[w] = p;
}

extern "C" void kernel_launch(void* const* d_in, const int* in_sizes, int n_in,
                              void* d_out, int out_size, void* d_ws, size_t ws_size,
                              hipStream_t stream) {
    const float* Gu       = (const float*)d_in[0];
    const float* Gi       = (const float*)d_in[1];
    const float* W0       = (const float*)d_in[2];
    const float* att_src0 = (const float*)d_in[3];
    const float* att_dst0 = (const float*)d_in[4];
    const float* b0       = (const float*)d_in[5];
    const float* W1       = (const float*)d_in[6];
    const float* att_src1 = (const float*)d_in[7];
    const float* att_dst1 = (const float*)d_in[8];
    const float* b1       = (const float*)d_in[9];
    const int* edge_index = (const int*)d_in[10];
    const int* user_idx   = (const int*)d_in[11];
    const int* item_idx   = (const int*)d_in[12];
    float* outp           = (float*)d_out;

    const int N = N_NODES, E = E_EDGES;
    char* wsp = (char*)d_ws;
    auto alloc = [&](size_t bytes) {
        void* p = wsp;
        wsp += (bytes + 255) & ~(size_t)255;
        return p;
    };
    float*  emb = (float*)alloc((size_t)N * 64 * 4);    // final embeddings
    __half* hh  = (__half*)alloc((size_t)N * 128 * 2);  // fp16 h (both layers)
    float*  x1  = (float*)alloc((size_t)N * 128 * 4);   // layer0 output (f32)
    float*  a_s = (float*)alloc((size_t)N * 2 * 4);
    float*  a_d = (float*)alloc((size_t)N * 2 * 4);
    int* row_ptr    = (int*)alloc((size_t)(N + 1) * 4);
    int* counts     = (int*)alloc((size_t)N * 4);
    int* bsums      = (int*)alloc(256 * 4);
    int* src_sorted = (int*)alloc((size_t)E * 4);
    int* bucket_ptr  = (int*)alloc((NBUCK + 1) * 4);
    int* gfill       = (int*)alloc((NBUCK + 1) * 4);
    // pk only lives during CSR build; x1 only after -> overlay (10.3MB << 41MB)
    unsigned long long* pk = (unsigned long long*)x1;

    const int* esrc = edge_index;
    const int* edst = edge_index + E;

    // row_ptr (exact-dst histogram + hierarchical scan)
    hipMemsetAsync(counts, 0, (size_t)N * 4, stream);
    hist_kernel<<<E / 256, 256, 0, stream>>>(edst, counts, E);
    int nb = (N + 1023) / 1024;
    scan_blocks_kernel<<<nb, 1024, 0, stream>>>(counts, row_ptr, bsums, N);
    scan_sums_kernel<<<1, 256, 0, stream>>>(bsums, nb);
    add_offsets_kernel<<<(N + 255) / 256, 256, 0, stream>>>(row_ptr, bsums, N);
    derive_buckets_kernel<<<(NBUCK + 256) / 256, 256, 0, stream>>>(row_ptr, bucket_ptr, gfill);

    // binned scatter -> src_sorted (CSR adjacency by dst)
    bscatter_kernel<<<(E + SCHUNK - 1) / SCHUNK, 512, 0, stream>>>(esrc, edst, gfill, pk, E);
    escatter_kernel<<<NBUCK, 256, 0, stream>>>(pk, bucket_ptr, row_ptr, src_sorted);

    // layer 0 (A read directly from Gu/Gi; h fp16 + att dots fused)
    gemm_kernel<64><<<N / 128, 256, 0, stream>>>(Gu, Gi, NU_NODES, W0, att_src0, att_dst0,
                                                 hh, a_s, a_d);
    gat_agg_kernel<true><<<(N + 3) / 4, 256, 0, stream>>>(hh, row_ptr, src_sorted, a_s, a_d,
                                                          b0, x1);

    // layer 1
    gemm_kernel<128><<<N / 128, 256, 0, stream>>>(x1, x1, N, W1, att_src1, att_dst1,
                                                  hh, a_s, a_d);
    gat_agg_kernel<false><<<(N + 3) / 4, 256, 0, stream>>>(hh, row_ptr, src_sorted, a_s, a_d,
                                                           b1, emb);

    // final dot
    pair_dot_kernel<<<B_PAIRS / 4, 256, 0, stream>>>(emb, user_idx, item_idx, outp, B_PAIRS);
}